// Round 2
// baseline (964.524 us; speedup 1.0000x reference)
//
#include <hip/hip_runtime.h>
#include <hip/hip_bf16.h>

#define N_V 6890
#define N_J 24
#define TB 16   // batches per block in main kernel

// SMPL kinematic tree: parent of joint i (i=1..23) is c_par[i-1]
__constant__ int c_par[23] = {0,0,0,1,2,3,4,5,6,7,8,9,9,9,12,13,14,16,17,18,19,20,21};

// ws layout (floats):
//   partial [24][8][33] @ 0      (6336)
//   JS      [24][30]    @ 6336   (720)
//   Jt      [24][3]     @ 7056   (72)
//   lrot    [B][207]    @ 7128
//   G       [B][24][12] @ 7128 + B*207
#define WS_PARTIAL 0
#define WS_JS      6336
#define WS_JT      7056
#define WS_LROT    7128

// ---------------- Kernel 1a: partial reduction for JS/Jt ----------------
__global__ void k_jreg_partial(const float* __restrict__ Jreg,
                               const float* __restrict__ shapedirs,
                               const float* __restrict__ v_template,
                               float* __restrict__ partial) {
    const int j = blockIdx.x;      // 0..23
    const int chunk = blockIdx.y;  // 0..7
    const int tid = threadIdx.x;   // 256
    const int per = (N_V + 7) / 8; // 862
    const int v0 = chunk * per;
    const int v1 = (v0 + per < N_V) ? (v0 + per) : N_V;

    float acc[33];
#pragma unroll
    for (int k = 0; k < 33; ++k) acc[k] = 0.f;

    for (int v = v0 + tid; v < v1; v += 256) {
        const float w = Jreg[j * N_V + v];
        const float* sd = shapedirs + (size_t)v * 30;
#pragma unroll
        for (int k = 0; k < 30; ++k) acc[k] += w * sd[k];
        acc[30] += w * v_template[v * 3 + 0];
        acc[31] += w * v_template[v * 3 + 1];
        acc[32] += w * v_template[v * 3 + 2];
    }

    // wave (64-lane) reduction
#pragma unroll
    for (int k = 0; k < 33; ++k) {
        float x = acc[k];
        for (int off = 32; off > 0; off >>= 1) x += __shfl_down(x, off);
        acc[k] = x;
    }
    __shared__ float red[4][33];
    const int wave = tid >> 6, lane = tid & 63;
    if (lane == 0) {
#pragma unroll
        for (int k = 0; k < 33; ++k) red[wave][k] = acc[k];
    }
    __syncthreads();
    if (tid < 33) {
        float s = red[0][tid] + red[1][tid] + red[2][tid] + red[3][tid];
        partial[(j * 8 + chunk) * 33 + tid] = s;
    }
}

// ---------------- Kernel 1b: final reduction -> JS, Jt ----------------
__global__ void k_jreg_final(const float* __restrict__ partial,
                             float* __restrict__ JS, float* __restrict__ Jt) {
    const int j = blockIdx.x;
    const int k = threadIdx.x;  // 64
    if (k < 33) {
        float s = 0.f;
#pragma unroll
        for (int c = 0; c < 8; ++c) s += partial[(j * 8 + c) * 33 + k];
        if (k < 30) JS[j * 30 + k] = s;
        else        Jt[j * 3 + (k - 30)] = s;
    }
}

// ---------------- Kernel 2: per-batch joints (Rodrigues + FK) ----------------
__global__ void k_joints(const float* __restrict__ pose, const float* __restrict__ beta,
                         const float* __restrict__ JS, const float* __restrict__ Jt,
                         float* __restrict__ lrot, float* __restrict__ Gout) {
    const int b = blockIdx.x;
    const int j = threadIdx.x;  // 64 threads, 0..23 active
    __shared__ float sJ[24][3];
    __shared__ float sG[24][12];

    float R[9];
    if (j < 24) {
        const float* bt = beta + b * 10;
#pragma unroll
        for (int c = 0; c < 3; ++c) {
            float s = Jt[j * 3 + c];
#pragma unroll
            for (int t = 0; t < 10; ++t) s += JS[j * 30 + c * 10 + t] * bt[t];
            sJ[j][c] = s;
        }
        const float rx = pose[b * 72 + 3 * j + 0];
        const float ry = pose[b * 72 + 3 * j + 1];
        const float rz = pose[b * 72 + 3 * j + 2];
        const float ang = sqrtf(rx * rx + ry * ry + rz * rz + 1e-8f);
        const float inv = 1.f / ang;
        const float x = rx * inv, y = ry * inv, z = rz * inv;
        const float c = cosf(ang), s = sinf(ang);
        const float ic = 1.f - c;
        R[0] = c + ic * x * x;  R[1] = ic * x * y - s * z; R[2] = ic * x * z + s * y;
        R[3] = ic * x * y + s * z; R[4] = c + ic * y * y;  R[5] = ic * y * z - s * x;
        R[6] = ic * x * z - s * y; R[7] = ic * y * z + s * x; R[8] = c + ic * z * z;
        if (j >= 1) {
            float* lr = lrot + (size_t)b * 207 + (j - 1) * 9;
#pragma unroll
            for (int k = 0; k < 9; ++k)
                lr[k] = R[k] - ((k == 0 || k == 4 || k == 8) ? 1.f : 0.f);
        }
    }
    __syncthreads();
    if (j < 24) {
        // local transform [R | J_rel]
        float t0, t1, t2;
        if (j == 0) { t0 = sJ[0][0]; t1 = sJ[0][1]; t2 = sJ[0][2]; }
        else {
            const int p = c_par[j - 1];
            t0 = sJ[j][0] - sJ[p][0]; t1 = sJ[j][1] - sJ[p][1]; t2 = sJ[j][2] - sJ[p][2];
        }
        sG[j][0] = R[0]; sG[j][1] = R[1]; sG[j][2]  = R[2]; sG[j][3]  = t0;
        sG[j][4] = R[3]; sG[j][5] = R[4]; sG[j][6]  = R[5]; sG[j][7]  = t1;
        sG[j][8] = R[6]; sG[j][9] = R[7]; sG[j][10] = R[8]; sG[j][11] = t2;
    }
    __syncthreads();
    if (j == 0) {
        // sequential FK (parents always precede children)
        for (int i = 1; i < 24; ++i) {
            const int p = c_par[i - 1];
            float P[12], L[12];
#pragma unroll
            for (int k = 0; k < 12; ++k) { P[k] = sG[p][k]; L[k] = sG[i][k]; }
#pragma unroll
            for (int m = 0; m < 3; ++m) {
#pragma unroll
                for (int n = 0; n < 3; ++n)
                    sG[i][m * 4 + n] = P[m * 4 + 0] * L[0 + n] + P[m * 4 + 1] * L[4 + n] + P[m * 4 + 2] * L[8 + n];
                sG[i][m * 4 + 3] = P[m * 4 + 0] * L[3] + P[m * 4 + 1] * L[7] + P[m * 4 + 2] * L[11] + P[m * 4 + 3];
            }
        }
    }
    __syncthreads();
    if (j < 24) {
        const float jx = sJ[j][0], jy = sJ[j][1], jz = sJ[j][2];
        float* go = Gout + (size_t)b * 288 + j * 12;
#pragma unroll
        for (int m = 0; m < 3; ++m) {
            const float corr = sG[j][m * 4 + 0] * jx + sG[j][m * 4 + 1] * jy + sG[j][m * 4 + 2] * jz;
            go[m * 4 + 0] = sG[j][m * 4 + 0];
            go[m * 4 + 1] = sG[j][m * 4 + 1];
            go[m * 4 + 2] = sG[j][m * 4 + 2];
            go[m * 4 + 3] = sG[j][m * 4 + 3] - corr;
        }
    }
}

// ---------------- Kernel 3: fused shape-blend + pose-blend + skinning ----------------
__global__ __launch_bounds__(256)
void k_main(const float* __restrict__ beta,
            const float* __restrict__ shapedirs,
            const float* __restrict__ posedirs,
            const float* __restrict__ v_template,
            const float* __restrict__ weights,
            const float* __restrict__ lrot,
            const float* __restrict__ Gbuf,
            float* __restrict__ out) {
    __shared__ float s_lrot[207 * TB];  // [p][t] (transposed for broadcast reads)
    __shared__ float s_G[TB * 288];     // [t][j][12]
    __shared__ float s_beta[TB * 10];   // [t][s]
    const int tid = threadIdx.x;
    const int b0 = blockIdx.y * TB;

    for (int i = tid; i < 207 * TB; i += 256) {
        const int t = i / 207, p = i - t * 207;
        s_lrot[p * TB + t] = lrot[(size_t)b0 * 207 + i];
    }
    for (int i = tid; i < TB * 288; i += 256) s_G[i] = Gbuf[(size_t)b0 * 288 + i];
    for (int i = tid; i < TB * 10; i += 256) s_beta[i] = beta[(size_t)b0 * 10 + i];
    __syncthreads();

    const int v = blockIdx.x * 256 + tid;
    if (v >= N_V) return;

    float acc0[TB], acc1[TB], acc2[TB];
    // ---- shape blend: v_shaped = v_template + shapedirs . beta ----
    {
        float sd[30];
        const float* sp = shapedirs + (size_t)v * 30;
#pragma unroll
        for (int k = 0; k < 30; ++k) sd[k] = sp[k];
        const float vt0 = v_template[v * 3 + 0];
        const float vt1 = v_template[v * 3 + 1];
        const float vt2 = v_template[v * 3 + 2];
#pragma unroll
        for (int t = 0; t < TB; ++t) {
            float a0 = vt0, a1 = vt1, a2 = vt2;
#pragma unroll
            for (int s = 0; s < 10; ++s) {
                const float bb = s_beta[t * 10 + s];
                a0 += sd[s] * bb; a1 += sd[10 + s] * bb; a2 += sd[20 + s] * bb;
            }
            acc0[t] = a0; acc1[t] = a1; acc2[t] = a2;
        }
    }
    // ---- pose blend: += posedirs[v,c,:] . lrotmin[b,:] ----
    {
        const float* pdb = posedirs + (size_t)v * 621;
#pragma unroll 3
        for (int p = 0; p < 207; ++p) {
            const float pd0 = pdb[p];
            const float pd1 = pdb[207 + p];
            const float pd2 = pdb[414 + p];
#pragma unroll
            for (int t = 0; t < TB; ++t) {
                const float l = s_lrot[p * TB + t];
                acc0[t] += pd0 * l; acc1[t] += pd1 * l; acc2[t] += pd2 * l;
            }
        }
    }
    // ---- skinning ----
    float w[24];
    {
        const float* wp = weights + (size_t)v * 24;
#pragma unroll
        for (int k = 0; k < 24; ++k) w[k] = wp[k];
    }
#pragma unroll
    for (int t = 0; t < TB; ++t) {
        float T[12];
#pragma unroll
        for (int k = 0; k < 12; ++k) T[k] = 0.f;
        const float* Gt = s_G + t * 288;
#pragma unroll
        for (int j = 0; j < 24; ++j) {
            const float wj = w[j];
#pragma unroll
            for (int k = 0; k < 12; ++k) T[k] += wj * Gt[j * 12 + k];
        }
        const float x = acc0[t], y = acc1[t], z = acc2[t];
        const float r0 = T[0] * x + T[1] * y + T[2]  * z + T[3];
        const float r1 = T[4] * x + T[5] * y + T[6]  * z + T[7];
        const float r2 = T[8] * x + T[9] * y + T[10] * z + T[11];
        const size_t o = ((size_t)(b0 + t) * N_V + v) * 3;
        out[o + 0] = r0;
        out[o + 1] = r1;
        out[o + 2] = r2;
    }
}

extern "C" void kernel_launch(void* const* d_in, const int* in_sizes, int n_in,
                              void* d_out, int out_size, void* d_ws, size_t ws_size,
                              hipStream_t stream) {
    const float* pose       = (const float*)d_in[0];
    const float* beta       = (const float*)d_in[1];
    const float* shapedirs  = (const float*)d_in[2];
    const float* posedirs   = (const float*)d_in[3];
    const float* v_template = (const float*)d_in[4];
    const float* Jreg       = (const float*)d_in[5];
    const float* weights    = (const float*)d_in[6];
    float* out = (float*)d_out;

    const int B = in_sizes[0] / 72;  // 1024

    float* ws      = (float*)d_ws;
    float* partial = ws + WS_PARTIAL;
    float* JS      = ws + WS_JS;
    float* Jt      = ws + WS_JT;
    float* lrot    = ws + WS_LROT;
    float* G       = ws + WS_LROT + (size_t)B * 207;

    k_jreg_partial<<<dim3(24, 8), 256, 0, stream>>>(Jreg, shapedirs, v_template, partial);
    k_jreg_final<<<24, 64, 0, stream>>>(partial, JS, Jt);
    k_joints<<<B, 64, 0, stream>>>(pose, beta, JS, Jt, lrot, G);
    k_main<<<dim3((N_V + 255) / 256, B / TB), 256, 0, stream>>>(
        beta, shapedirs, posedirs, v_template, weights, lrot, G, out);
}

// Round 3
// 211.794 us; speedup vs baseline: 4.5541x; 4.5541x over previous
//
#include <hip/hip_runtime.h>
#include <hip/hip_bf16.h>

#define N_V 6890
#define N_J 24
#define NPAD 20736   // 162*128, padded N for GEMM
#define NREAL 20670  // N_V*3
#define KDIM 224     // 207 lrot + 10 beta + 1 template + 6 zero pad
#define BM 128
#define BN 128
#define BK 32

typedef __attribute__((ext_vector_type(8))) short bf16x8;
typedef __attribute__((ext_vector_type(4))) float f32x4;

__constant__ int c_par[23] = {0,0,0,1,2,3,4,5,6,7,8,9,9,9,12,13,14,16,17,18,19,20,21};

static __device__ __forceinline__ unsigned short f2bf(float f) {
    unsigned int u = __float_as_uint(f);
    unsigned int r = (u + 0x7fffu + ((u >> 16) & 1u)) >> 16;
    return (unsigned short)r;
}

// ws layout:
//   floats: partial[6336] @0, JS[720] @6336, Jt[72] @7056, G[1024*288] @7128
//   ushort: Amat[1024*224] @float ofs 302040, Bmat[20736*224] after
#define WS_PARTIAL 0
#define WS_JS      6336
#define WS_JT      7056
#define WS_G       7128
#define WS_AMAT_F  302040   // float-index where ushort region starts

// ---------------- Kernel 1a: partial reduction for J_regressor ----------------
__global__ void k_jreg_partial(const float* __restrict__ Jreg,
                               const float* __restrict__ shapedirs,
                               const float* __restrict__ v_template,
                               float* __restrict__ partial) {
    const int j = blockIdx.x, chunk = blockIdx.y, tid = threadIdx.x;
    const int per = (N_V + 7) / 8;
    const int v0 = chunk * per;
    const int v1 = (v0 + per < N_V) ? (v0 + per) : N_V;
    float acc[33];
#pragma unroll
    for (int k = 0; k < 33; ++k) acc[k] = 0.f;
    for (int v = v0 + tid; v < v1; v += 256) {
        const float w = Jreg[j * N_V + v];
        const float* sd = shapedirs + (size_t)v * 30;
#pragma unroll
        for (int k = 0; k < 30; ++k) acc[k] += w * sd[k];
        acc[30] += w * v_template[v * 3 + 0];
        acc[31] += w * v_template[v * 3 + 1];
        acc[32] += w * v_template[v * 3 + 2];
    }
#pragma unroll
    for (int k = 0; k < 33; ++k) {
        float x = acc[k];
        for (int off = 32; off > 0; off >>= 1) x += __shfl_down(x, off);
        acc[k] = x;
    }
    __shared__ float red[4][33];
    const int wave = tid >> 6, lane = tid & 63;
    if (lane == 0) {
#pragma unroll
        for (int k = 0; k < 33; ++k) red[wave][k] = acc[k];
    }
    __syncthreads();
    if (tid < 33) {
        partial[(j * 8 + chunk) * 33 + tid] =
            red[0][tid] + red[1][tid] + red[2][tid] + red[3][tid];
    }
}

__global__ void k_jreg_final(const float* __restrict__ partial,
                             float* __restrict__ JS, float* __restrict__ Jt) {
    const int j = blockIdx.x, k = threadIdx.x;
    if (k < 33) {
        float s = 0.f;
#pragma unroll
        for (int c = 0; c < 8; ++c) s += partial[(j * 8 + c) * 33 + k];
        if (k < 30) JS[j * 30 + k] = s;
        else        Jt[j * 3 + (k - 30)] = s;
    }
}

// ---------------- Kernel 2: Bmat = [posedirs | shapedirs | v_template | 0] bf16 ----------------
__global__ void k_bmat(const float* __restrict__ posedirs,
                       const float* __restrict__ shapedirs,
                       const float* __restrict__ v_template,
                       unsigned short* __restrict__ Bmat) {
    const int n = blockIdx.x;
    const int k = threadIdx.x;
    if (k >= KDIM) return;
    float val = 0.f;
    if (n < NREAL) {
        if (k < 207)      val = posedirs[(size_t)n * 207 + k];
        else if (k < 217) val = shapedirs[(size_t)n * 10 + (k - 207)];
        else if (k == 217) val = v_template[n];
    }
    Bmat[(size_t)n * KDIM + k] = f2bf(val);
}

// ---------------- Kernel 3: per-batch joints: Rodrigues + FK + Amat ----------------
__global__ void k_joints(const float* __restrict__ pose, const float* __restrict__ beta,
                         const float* __restrict__ JS, const float* __restrict__ Jt,
                         unsigned short* __restrict__ Amat, float* __restrict__ Gout) {
    const int b = blockIdx.x;
    const int j = threadIdx.x;  // 64 threads
    __shared__ float sJ[24][3];
    __shared__ float sG[24][12];
    float R[9];
    if (j < 24) {
        const float* bt = beta + b * 10;
#pragma unroll
        for (int c = 0; c < 3; ++c) {
            float s = Jt[j * 3 + c];
#pragma unroll
            for (int t = 0; t < 10; ++t) s += JS[j * 30 + c * 10 + t] * bt[t];
            sJ[j][c] = s;
        }
        const float rx = pose[b * 72 + 3 * j + 0];
        const float ry = pose[b * 72 + 3 * j + 1];
        const float rz = pose[b * 72 + 3 * j + 2];
        const float ang = sqrtf(rx * rx + ry * ry + rz * rz + 1e-8f);
        const float inv = 1.f / ang;
        const float x = rx * inv, y = ry * inv, z = rz * inv;
        const float c = cosf(ang), s = sinf(ang);
        const float ic = 1.f - c;
        R[0] = c + ic * x * x;     R[1] = ic * x * y - s * z; R[2] = ic * x * z + s * y;
        R[3] = ic * x * y + s * z; R[4] = c + ic * y * y;     R[5] = ic * y * z - s * x;
        R[6] = ic * x * z - s * y; R[7] = ic * y * z + s * x; R[8] = c + ic * z * z;
        if (j >= 1) {
            unsigned short* ar = Amat + (size_t)b * KDIM + (j - 1) * 9;
#pragma unroll
            for (int k = 0; k < 9; ++k)
                ar[k] = f2bf(R[k] - ((k == 0 || k == 4 || k == 8) ? 1.f : 0.f));
        }
    } else if (j < 41) {
        // k = 207..223: beta(10), 1.0, zeros(6)
        const int k = 207 + (j - 24);
        float val = (k < 217) ? beta[b * 10 + (k - 207)] : (k == 217 ? 1.f : 0.f);
        Amat[(size_t)b * KDIM + k] = f2bf(val);
    }
    __syncthreads();
    if (j < 24) {
        float t0, t1, t2;
        if (j == 0) { t0 = sJ[0][0]; t1 = sJ[0][1]; t2 = sJ[0][2]; }
        else {
            const int p = c_par[j - 1];
            t0 = sJ[j][0] - sJ[p][0]; t1 = sJ[j][1] - sJ[p][1]; t2 = sJ[j][2] - sJ[p][2];
        }
        sG[j][0] = R[0]; sG[j][1] = R[1]; sG[j][2]  = R[2]; sG[j][3]  = t0;
        sG[j][4] = R[3]; sG[j][5] = R[4]; sG[j][6]  = R[5]; sG[j][7]  = t1;
        sG[j][8] = R[6]; sG[j][9] = R[7]; sG[j][10] = R[8]; sG[j][11] = t2;
    }
    __syncthreads();
    if (j == 0) {
        for (int i = 1; i < 24; ++i) {
            const int p = c_par[i - 1];
            float P[12], L[12];
#pragma unroll
            for (int k = 0; k < 12; ++k) { P[k] = sG[p][k]; L[k] = sG[i][k]; }
#pragma unroll
            for (int m = 0; m < 3; ++m) {
#pragma unroll
                for (int n = 0; n < 3; ++n)
                    sG[i][m * 4 + n] = P[m * 4] * L[n] + P[m * 4 + 1] * L[4 + n] + P[m * 4 + 2] * L[8 + n];
                sG[i][m * 4 + 3] = P[m * 4] * L[3] + P[m * 4 + 1] * L[7] + P[m * 4 + 2] * L[11] + P[m * 4 + 3];
            }
        }
    }
    __syncthreads();
    if (j < 24) {
        const float jx = sJ[j][0], jy = sJ[j][1], jz = sJ[j][2];
        float* go = Gout + (size_t)b * 288 + j * 12;
#pragma unroll
        for (int m = 0; m < 3; ++m) {
            const float corr = sG[j][m * 4] * jx + sG[j][m * 4 + 1] * jy + sG[j][m * 4 + 2] * jz;
            go[m * 4 + 0] = sG[j][m * 4 + 0];
            go[m * 4 + 1] = sG[j][m * 4 + 1];
            go[m * 4 + 2] = sG[j][m * 4 + 2];
            go[m * 4 + 3] = sG[j][m * 4 + 3] - corr;
        }
    }
}

// ---------------- Kernel 4: GEMM  C[b][n] = A[b][:] . Bmat[n][:]  (B^T input) ----------------
// M=1024 (b), N=20736 padded (n), K=224. Writes v_posed to d_out (cols < NREAL).
__global__ __launch_bounds__(256)
void k_gemm(const unsigned short* __restrict__ Amat,
            const unsigned short* __restrict__ Bmat,
            float* __restrict__ out) {
    __shared__ unsigned short sA[BM * BK];  // [row][k] 64B rows
    __shared__ unsigned short sB[BN * BK];
    const int tid = threadIdx.x;
    const int wid = tid >> 6, l = tid & 63;
    const int wrow = (wid >> 1) * 64, wcol = (wid & 1) * 64;
    const int n0 = blockIdx.x * BN;
    const int m0 = blockIdx.y * BM;

    f32x4 acc[4][4];
#pragma unroll
    for (int i = 0; i < 4; ++i)
#pragma unroll
        for (int j = 0; j < 4; ++j) acc[i][j] = (f32x4){0.f, 0.f, 0.f, 0.f};

    // staging map: chunk c = tid + 256*i ; row = c>>2, u = c&3 (8 bf16 units)
    for (int ks = 0; ks < KDIM / BK; ++ks) {
        const int kbase = ks * BK;
        bf16x8 ra[2], rb[2];
#pragma unroll
        for (int i = 0; i < 2; ++i) {
            const int c = tid + 256 * i;
            const int row = c >> 2, u = c & 3;
            ra[i] = *(const bf16x8*)&Amat[(size_t)(m0 + row) * KDIM + kbase + u * 8];
            rb[i] = *(const bf16x8*)&Bmat[(size_t)(n0 + row) * KDIM + kbase + u * 8];
        }
        __syncthreads();  // previous compute done before overwrite
#pragma unroll
        for (int i = 0; i < 2; ++i) {
            const int c = tid + 256 * i;
            const int row = c >> 2, u = c & 3;
            *(bf16x8*)&sA[row * BK + u * 8] = ra[i];
            *(bf16x8*)&sB[row * BK + u * 8] = rb[i];
        }
        __syncthreads();

        bf16x8 af[4], bf[4];
#pragma unroll
        for (int mi = 0; mi < 4; ++mi)
            af[mi] = *(const bf16x8*)&sA[(wrow + mi * 16 + (l & 15)) * BK + (l >> 4) * 8];
#pragma unroll
        for (int ni = 0; ni < 4; ++ni)
            bf[ni] = *(const bf16x8*)&sB[(wcol + ni * 16 + (l & 15)) * BK + (l >> 4) * 8];
#pragma unroll
        for (int mi = 0; mi < 4; ++mi)
#pragma unroll
            for (int ni = 0; ni < 4; ++ni)
                acc[mi][ni] = __builtin_amdgcn_mfma_f32_16x16x32_bf16(af[mi], bf[ni], acc[mi][ni], 0, 0, 0);
    }

    // epilogue: C[row][col], row=(lane>>4)*4+reg, col=lane&15 per frag
    const int row_base = m0 + wrow + (l >> 4) * 4;
    const int col_base = n0 + wcol + (l & 15);
#pragma unroll
    for (int mi = 0; mi < 4; ++mi) {
#pragma unroll
        for (int ni = 0; ni < 4; ++ni) {
            const int col = col_base + ni * 16;
            if (col < NREAL) {
#pragma unroll
                for (int r = 0; r < 4; ++r)
                    out[(size_t)(row_base + mi * 16 + r) * NREAL + col] = acc[mi][ni][r];
            }
        }
    }
}

// ---------------- Kernel 5: in-place skinning on d_out ----------------
#define SK_TB 8
__global__ __launch_bounds__(256)
void k_skin(const float* __restrict__ weights, const float* __restrict__ G,
            float* __restrict__ out) {
    const int tid = threadIdx.x;
    const int v = blockIdx.x * 256 + tid;
    const int b0 = blockIdx.y * SK_TB;
    if (v >= N_V) return;

    float w[24];
    {
        const float4* wp = (const float4*)(weights + (size_t)v * 24);
#pragma unroll
        for (int i = 0; i < 6; ++i) {
            const float4 q = wp[i];
            w[i * 4 + 0] = q.x; w[i * 4 + 1] = q.y; w[i * 4 + 2] = q.z; w[i * 4 + 3] = q.w;
        }
    }
#pragma unroll
    for (int t = 0; t < SK_TB; ++t) {
        const int b = b0 + t;
        const float* Gb = G + (size_t)b * 288;  // wave-uniform -> scalar loads
        float T[12];
#pragma unroll
        for (int k = 0; k < 12; ++k) T[k] = w[0] * Gb[k];
#pragma unroll
        for (int j = 1; j < 24; ++j) {
            const float wj = w[j];
#pragma unroll
            for (int k = 0; k < 12; ++k) T[k] += wj * Gb[j * 12 + k];
        }
        float* o = out + (size_t)b * NREAL + v * 3;
        const float x = o[0], y = o[1], z = o[2];
        o[0] = T[0] * x + T[1] * y + T[2]  * z + T[3];
        o[1] = T[4] * x + T[5] * y + T[6]  * z + T[7];
        o[2] = T[8] * x + T[9] * y + T[10] * z + T[11];
    }
}

extern "C" void kernel_launch(void* const* d_in, const int* in_sizes, int n_in,
                              void* d_out, int out_size, void* d_ws, size_t ws_size,
                              hipStream_t stream) {
    const float* pose       = (const float*)d_in[0];
    const float* beta       = (const float*)d_in[1];
    const float* shapedirs  = (const float*)d_in[2];
    const float* posedirs   = (const float*)d_in[3];
    const float* v_template = (const float*)d_in[4];
    const float* Jreg       = (const float*)d_in[5];
    const float* weights    = (const float*)d_in[6];
    float* out = (float*)d_out;

    const int B = in_sizes[0] / 72;  // 1024

    float* ws      = (float*)d_ws;
    float* partial = ws + WS_PARTIAL;
    float* JS      = ws + WS_JS;
    float* Jt      = ws + WS_JT;
    float* G       = ws + WS_G;
    unsigned short* Amat = (unsigned short*)(ws + WS_AMAT_F);
    unsigned short* Bmat = Amat + (size_t)B * KDIM;

    k_jreg_partial<<<dim3(24, 8), 256, 0, stream>>>(Jreg, shapedirs, v_template, partial);
    k_jreg_final<<<24, 64, 0, stream>>>(partial, JS, Jt);
    k_bmat<<<NPAD, 256, 0, stream>>>(posedirs, shapedirs, v_template, Bmat);
    k_joints<<<B, 64, 0, stream>>>(pose, beta, JS, Jt, Amat, G);
    k_gemm<<<dim3(NPAD / BN, B / BM), 256, 0, stream>>>(Amat, Bmat, out);
    k_skin<<<dim3((N_V + 255) / 256, B / SK_TB), 256, 0, stream>>>(weights, G, out);
}

// Round 4
// 123.217 us; speedup vs baseline: 7.8278x; 1.7189x over previous
//
#include <hip/hip_runtime.h>
#include <hip/hip_bf16.h>

#define N_V 6890
#define NVPAD 6912   // padded vertex count (54*128) for skin kernel
#define N_J 24
#define NPAD 20736   // 162*128, padded N for GEMM
#define NREAL 20670  // N_V*3
#define KDIM 224     // 207 lrot + 10 beta + 1 template + 6 zero pad
#define BM 128
#define BN 128
#define BK 32
#define SK_BCH 32    // batches per block in skin kernel

typedef __attribute__((ext_vector_type(8))) short bf16x8;
typedef __attribute__((ext_vector_type(4))) float f32x4;

__constant__ int c_par[23] = {0,0,0,1,2,3,4,5,6,7,8,9,9,9,12,13,14,16,17,18,19,20,21};

static __device__ __forceinline__ unsigned short f2bf(float f) {
    unsigned int u = __float_as_uint(f);
    unsigned int r = (u + 0x7fffu + ((u >> 16) & 1u)) >> 16;
    return (unsigned short)r;
}

// ws layout:
//   floats: partial[6336] @0, JS[720] @6336, Jt[72] @7056, G[1024*288] @7128  (end 302040)
//   ushort region @ float ofs 302040:
//     Amat [1024*224]       @0
//     Bmat [20736*224]      @229376
//     Gbf  [1024][16][32]   @4874240   (A-frag-ready transposed, zero-padded)
//     Wbf  [6912][32]       @5398528   (zero-padded)
#define WS_PARTIAL 0
#define WS_JS      6336
#define WS_JT      7056
#define WS_G       7128
#define WS_AMAT_F  302040
#define U_AMAT 0
#define U_BMAT 229376
#define U_GBF  4874240
#define U_WBF  5398528

// ---------------- Kernel 1a: partial reduction for J_regressor ----------------
__global__ void k_jreg_partial(const float* __restrict__ Jreg,
                               const float* __restrict__ shapedirs,
                               const float* __restrict__ v_template,
                               float* __restrict__ partial) {
    const int j = blockIdx.x, chunk = blockIdx.y, tid = threadIdx.x;
    const int per = (N_V + 7) / 8;
    const int v0 = chunk * per;
    const int v1 = (v0 + per < N_V) ? (v0 + per) : N_V;
    float acc[33];
#pragma unroll
    for (int k = 0; k < 33; ++k) acc[k] = 0.f;
    for (int v = v0 + tid; v < v1; v += 256) {
        const float w = Jreg[j * N_V + v];
        const float* sd = shapedirs + (size_t)v * 30;
#pragma unroll
        for (int k = 0; k < 30; ++k) acc[k] += w * sd[k];
        acc[30] += w * v_template[v * 3 + 0];
        acc[31] += w * v_template[v * 3 + 1];
        acc[32] += w * v_template[v * 3 + 2];
    }
#pragma unroll
    for (int k = 0; k < 33; ++k) {
        float x = acc[k];
        for (int off = 32; off > 0; off >>= 1) x += __shfl_down(x, off);
        acc[k] = x;
    }
    __shared__ float red[4][33];
    const int wave = tid >> 6, lane = tid & 63;
    if (lane == 0) {
#pragma unroll
        for (int k = 0; k < 33; ++k) red[wave][k] = acc[k];
    }
    __syncthreads();
    if (tid < 33) {
        partial[(j * 8 + chunk) * 33 + tid] =
            red[0][tid] + red[1][tid] + red[2][tid] + red[3][tid];
    }
}

__global__ void k_jreg_final(const float* __restrict__ partial,
                             float* __restrict__ JS, float* __restrict__ Jt) {
    const int j = blockIdx.x, k = threadIdx.x;
    if (k < 33) {
        float s = 0.f;
#pragma unroll
        for (int c = 0; c < 8; ++c) s += partial[(j * 8 + c) * 33 + k];
        if (k < 30) JS[j * 30 + k] = s;
        else        Jt[j * 3 + (k - 30)] = s;
    }
}

// ---------------- Kernel 2: Bmat = [posedirs | shapedirs | v_template | 0] bf16 ----------------
static __device__ __forceinline__ float bval(const float* pd, const float* sd,
                                             const float* vt, int n, int k) {
    if (n >= NREAL) return 0.f;
    if (k < 207)  return pd[(size_t)n * 207 + k];
    if (k < 217)  return sd[(size_t)n * 10 + (k - 207)];
    if (k == 217) return vt[n];
    return 0.f;
}

__global__ void k_bmat(const float* __restrict__ posedirs,
                       const float* __restrict__ shapedirs,
                       const float* __restrict__ v_template,
                       unsigned short* __restrict__ Bmat) {
    const int n = blockIdx.x;
    const int t = threadIdx.x;  // 128, covers k = 2t, 2t+1
    if (2 * t >= KDIM) return;
    ushort2 o;
    o.x = f2bf(bval(posedirs, shapedirs, v_template, n, 2 * t));
    o.y = f2bf(bval(posedirs, shapedirs, v_template, n, 2 * t + 1));
    *(ushort2*)&Bmat[(size_t)n * KDIM + 2 * t] = o;
}

// ---------------- Kernel 2b: Wbf[v][32] bf16 zero-padded ----------------
__global__ void k_wbf(const float* __restrict__ weights, unsigned short* __restrict__ Wbf) {
    const int idx = blockIdx.x * 256 + threadIdx.x;
    if (idx >= NVPAD * 32) return;
    const int v = idx >> 5, k = idx & 31;
    float val = (v < N_V && k < 24) ? weights[(size_t)v * 24 + k] : 0.f;
    Wbf[idx] = f2bf(val);
}

// ---------------- Kernel 3: per-batch joints: Rodrigues + FK + Amat + Gbf ----------------
__global__ void k_joints(const float* __restrict__ pose, const float* __restrict__ beta,
                         const float* __restrict__ JS, const float* __restrict__ Jt,
                         unsigned short* __restrict__ Amat, float* __restrict__ Gout,
                         unsigned short* __restrict__ Gbf) {
    const int b = blockIdx.x;
    const int j = threadIdx.x;  // 64 threads
    __shared__ float sJ[24][3];
    __shared__ float sG[24][12];

    // zero-fill ONLY the pad entries of Gbf (no overlap with real writes below)
    // pads: (mn 12..15, j 0..31) -> 128 entries; (mn 0..11, j 24..31) -> 96 entries
    for (int idx = j; idx < 224; idx += 64) {
        int mn, jj;
        if (idx < 128) { mn = 12 + (idx >> 5); jj = idx & 31; }
        else { const int q = idx - 128; mn = q >> 3; jj = 24 + (q & 7); }
        Gbf[(size_t)b * 512 + mn * 32 + jj] = 0;
    }

    float R[9];
    if (j < 24) {
        const float* bt = beta + b * 10;
#pragma unroll
        for (int c = 0; c < 3; ++c) {
            float s = Jt[j * 3 + c];
#pragma unroll
            for (int t = 0; t < 10; ++t) s += JS[j * 30 + c * 10 + t] * bt[t];
            sJ[j][c] = s;
        }
        const float rx = pose[b * 72 + 3 * j + 0];
        const float ry = pose[b * 72 + 3 * j + 1];
        const float rz = pose[b * 72 + 3 * j + 2];
        const float ang = sqrtf(rx * rx + ry * ry + rz * rz + 1e-8f);
        const float inv = 1.f / ang;
        const float x = rx * inv, y = ry * inv, z = rz * inv;
        const float c = cosf(ang), s = sinf(ang);
        const float ic = 1.f - c;
        R[0] = c + ic * x * x;     R[1] = ic * x * y - s * z; R[2] = ic * x * z + s * y;
        R[3] = ic * x * y + s * z; R[4] = c + ic * y * y;     R[5] = ic * y * z - s * x;
        R[6] = ic * x * z - s * y; R[7] = ic * y * z + s * x; R[8] = c + ic * z * z;
        if (j >= 1) {
            unsigned short* ar = Amat + (size_t)b * KDIM + (j - 1) * 9;
#pragma unroll
            for (int k = 0; k < 9; ++k)
                ar[k] = f2bf(R[k] - ((k == 0 || k == 4 || k == 8) ? 1.f : 0.f));
        }
    } else if (j < 41) {
        const int k = 207 + (j - 24);
        float val = (k < 217) ? beta[b * 10 + (k - 207)] : (k == 217 ? 1.f : 0.f);
        Amat[(size_t)b * KDIM + k] = f2bf(val);
    }
    __syncthreads();
    if (j < 24) {
        float t0, t1, t2;
        if (j == 0) { t0 = sJ[0][0]; t1 = sJ[0][1]; t2 = sJ[0][2]; }
        else {
            const int p = c_par[j - 1];
            t0 = sJ[j][0] - sJ[p][0]; t1 = sJ[j][1] - sJ[p][1]; t2 = sJ[j][2] - sJ[p][2];
        }
        sG[j][0] = R[0]; sG[j][1] = R[1]; sG[j][2]  = R[2]; sG[j][3]  = t0;
        sG[j][4] = R[3]; sG[j][5] = R[4]; sG[j][6]  = R[5]; sG[j][7]  = t1;
        sG[j][8] = R[6]; sG[j][9] = R[7]; sG[j][10] = R[8]; sG[j][11] = t2;
    }
    __syncthreads();
    if (j == 0) {
        for (int i = 1; i < 24; ++i) {
            const int p = c_par[i - 1];
            float P[12], L[12];
#pragma unroll
            for (int k = 0; k < 12; ++k) { P[k] = sG[p][k]; L[k] = sG[i][k]; }
#pragma unroll
            for (int m = 0; m < 3; ++m) {
#pragma unroll
                for (int n = 0; n < 3; ++n)
                    sG[i][m * 4 + n] = P[m * 4] * L[n] + P[m * 4 + 1] * L[4 + n] + P[m * 4 + 2] * L[8 + n];
                sG[i][m * 4 + 3] = P[m * 4] * L[3] + P[m * 4 + 1] * L[7] + P[m * 4 + 2] * L[11] + P[m * 4 + 3];
            }
        }
    }
    __syncthreads();
    if (j < 24) {
        const float jx = sJ[j][0], jy = sJ[j][1], jz = sJ[j][2];
        float* go = Gout + (size_t)b * 288 + j * 12;
#pragma unroll
        for (int m = 0; m < 3; ++m) {
            const float corr = sG[j][m * 4] * jx + sG[j][m * 4 + 1] * jy + sG[j][m * 4 + 2] * jz;
            const float g0 = sG[j][m * 4 + 0];
            const float g1 = sG[j][m * 4 + 1];
            const float g2 = sG[j][m * 4 + 2];
            const float g3 = sG[j][m * 4 + 3] - corr;
            go[m * 4 + 0] = g0; go[m * 4 + 1] = g1; go[m * 4 + 2] = g2; go[m * 4 + 3] = g3;
            // transposed bf16 copy for skin MFMA A-operand: Gbf[b][mn][j]
            Gbf[(size_t)b * 512 + (m * 4 + 0) * 32 + j] = f2bf(g0);
            Gbf[(size_t)b * 512 + (m * 4 + 1) * 32 + j] = f2bf(g1);
            Gbf[(size_t)b * 512 + (m * 4 + 2) * 32 + j] = f2bf(g2);
            Gbf[(size_t)b * 512 + (m * 4 + 3) * 32 + j] = f2bf(g3);
        }
    }
}

// ---------------- Kernel 4: GEMM  C[b][n] = A[b][:] . Bmat[n][:] -> d_out (v_posed) ----------------
__global__ __launch_bounds__(256)
void k_gemm(const unsigned short* __restrict__ Amat,
            const unsigned short* __restrict__ Bmat,
            float* __restrict__ out) {
    __shared__ unsigned short sA[BM * BK];
    __shared__ unsigned short sB[BN * BK];
    const int tid = threadIdx.x;
    const int wid = tid >> 6, l = tid & 63;
    const int wrow = (wid >> 1) * 64, wcol = (wid & 1) * 64;
    const int n0 = blockIdx.x * BN;
    const int m0 = blockIdx.y * BM;

    f32x4 acc[4][4];
#pragma unroll
    for (int i = 0; i < 4; ++i)
#pragma unroll
        for (int j = 0; j < 4; ++j) acc[i][j] = (f32x4){0.f, 0.f, 0.f, 0.f};

    for (int ks = 0; ks < KDIM / BK; ++ks) {
        const int kbase = ks * BK;
        bf16x8 ra[2], rb[2];
#pragma unroll
        for (int i = 0; i < 2; ++i) {
            const int c = tid + 256 * i;
            const int row = c >> 2, u = c & 3;
            ra[i] = *(const bf16x8*)&Amat[(size_t)(m0 + row) * KDIM + kbase + u * 8];
            rb[i] = *(const bf16x8*)&Bmat[(size_t)(n0 + row) * KDIM + kbase + u * 8];
        }
        __syncthreads();
#pragma unroll
        for (int i = 0; i < 2; ++i) {
            const int c = tid + 256 * i;
            const int row = c >> 2, u = c & 3;
            *(bf16x8*)&sA[row * BK + u * 8] = ra[i];
            *(bf16x8*)&sB[row * BK + u * 8] = rb[i];
        }
        __syncthreads();

        bf16x8 af[4], bf[4];
#pragma unroll
        for (int mi = 0; mi < 4; ++mi)
            af[mi] = *(const bf16x8*)&sA[(wrow + mi * 16 + (l & 15)) * BK + (l >> 4) * 8];
#pragma unroll
        for (int ni = 0; ni < 4; ++ni)
            bf[ni] = *(const bf16x8*)&sB[(wcol + ni * 16 + (l & 15)) * BK + (l >> 4) * 8];
#pragma unroll
        for (int mi = 0; mi < 4; ++mi)
#pragma unroll
            for (int ni = 0; ni < 4; ++ni)
                acc[mi][ni] = __builtin_amdgcn_mfma_f32_16x16x32_bf16(af[mi], bf[ni], acc[mi][ni], 0, 0, 0);
    }

    const int row_base = m0 + wrow + (l >> 4) * 4;
    const int col_base = n0 + wcol + (l & 15);
#pragma unroll
    for (int mi = 0; mi < 4; ++mi) {
#pragma unroll
        for (int ni = 0; ni < 4; ++ni) {
            const int col = col_base + ni * 16;
            if (col < NREAL) {
#pragma unroll
                for (int r = 0; r < 4; ++r)
                    out[(size_t)(row_base + mi * 16 + r) * NREAL + col] = acc[mi][ni][r];
            }
        }
    }
}

// ---------------- Kernel 5: MFMA skinning, in-place on d_out ----------------
// Per (batch, 16-vertex group): C = A(Gbf[b] 16x32) x B(Wbf^T 32x16).
// Lane l: c=l&15 (vertex), p=l>>4 (output row m for p<3); acc[0..3] = T[p][0..3].
__global__ __launch_bounds__(256)
void k_skin(const unsigned short* __restrict__ Gbf,
            const unsigned short* __restrict__ Wbf,
            float* __restrict__ out) {
    const int tid = threadIdx.x;
    const int wid = tid >> 6, l = tid & 63;
    const int vb = blockIdx.x * 128 + wid * 32;   // this wave's 32 vertices
    const int b0 = blockIdx.y * SK_BCH;
    const int c = l & 15, p = l >> 4;

    // B-frags for the wave's two vertex groups (loop-invariant)
    const int koff = p * 8;  // (l>>4)*8
    const bf16x8 bw0 = *(const bf16x8*)&Wbf[(size_t)(vb + c) * 32 + koff];
    const bf16x8 bw1 = *(const bf16x8*)&Wbf[(size_t)(vb + 16 + c) * 32 + koff];

    const int agofs = c * 32 + koff;  // A-frag: row=l&15, k=(l>>4)*8
    bf16x8 ag = *(const bf16x8*)&Gbf[(size_t)b0 * 512 + agofs];

    for (int b = b0; b < b0 + SK_BCH; ++b) {
        bf16x8 agn = ag;
        if (b + 1 < b0 + SK_BCH)
            agn = *(const bf16x8*)&Gbf[(size_t)(b + 1) * 512 + agofs];

        f32x4 acc0 = __builtin_amdgcn_mfma_f32_16x16x32_bf16(ag, bw0, (f32x4){0.f,0.f,0.f,0.f}, 0, 0, 0);
        f32x4 acc1 = __builtin_amdgcn_mfma_f32_16x16x32_bf16(ag, bw1, (f32x4){0.f,0.f,0.f,0.f}, 0, 0, 0);

#pragma unroll
        for (int g = 0; g < 2; ++g) {
            const f32x4 a = g ? acc1 : acc0;
            const int v = vb + g * 16 + c;
            float x = 0.f, y = 0.f, z = 0.f;
            if (v < N_V) {
                const float* vp = out + (size_t)b * NREAL + v * 3;
                x = vp[0]; y = vp[1]; z = vp[2];
            }
            const float r = a[0] * x + a[1] * y + a[2] * z + a[3];
            if (v < N_V && p < 3)
                out[(size_t)b * NREAL + v * 3 + p] = r;
        }
        ag = agn;
    }
}

extern "C" void kernel_launch(void* const* d_in, const int* in_sizes, int n_in,
                              void* d_out, int out_size, void* d_ws, size_t ws_size,
                              hipStream_t stream) {
    const float* pose       = (const float*)d_in[0];
    const float* beta       = (const float*)d_in[1];
    const float* shapedirs  = (const float*)d_in[2];
    const float* posedirs   = (const float*)d_in[3];
    const float* v_template = (const float*)d_in[4];
    const float* Jreg       = (const float*)d_in[5];
    const float* weights    = (const float*)d_in[6];
    float* out = (float*)d_out;

    const int B = in_sizes[0] / 72;  // 1024

    float* ws      = (float*)d_ws;
    float* partial = ws + WS_PARTIAL;
    float* JS      = ws + WS_JS;
    float* Jt      = ws + WS_JT;
    float* G       = ws + WS_G;
    unsigned short* ubase = (unsigned short*)(ws + WS_AMAT_F);
    unsigned short* Amat = ubase + U_AMAT;
    unsigned short* Bmat = ubase + U_BMAT;
    unsigned short* Gbf  = ubase + U_GBF;
    unsigned short* Wbf  = ubase + U_WBF;

    k_jreg_partial<<<dim3(24, 8), 256, 0, stream>>>(Jreg, shapedirs, v_template, partial);
    k_jreg_final<<<24, 64, 0, stream>>>(partial, JS, Jt);
    k_bmat<<<NPAD, 128, 0, stream>>>(posedirs, shapedirs, v_template, Bmat);
    k_wbf<<<(NVPAD * 32 + 255) / 256, 256, 0, stream>>>(weights, Wbf);
    k_joints<<<B, 64, 0, stream>>>(pose, beta, JS, Jt, Amat, G, Gbf);
    k_gemm<<<dim3(NPAD / BN, B / BM), 256, 0, stream>>>(Amat, Bmat, out);
    k_skin<<<dim3(NVPAD / 128, B / SK_BCH), 256, 0, stream>>>(Gbf, Wbf, out);
}

// Round 5
// 100.745 us; speedup vs baseline: 9.5739x; 1.2231x over previous
//
#include <hip/hip_runtime.h>
#include <hip/hip_bf16.h>

#define N_V 6890
#define NVPAD 6912   // padded vertex count (216*32)
#define N_J 24
#define NPAD 20736   // 216*96, padded N for GEMM
#define NREAL 20670  // N_V*3
#define KDIM 224     // 207 lrot + 10 beta + 1 template + 6 zero pad
#define BK 32
#define FB 128       // batches per fused block
#define FV 32        // vertices per fused block (96 GEMM columns)

typedef __attribute__((ext_vector_type(8))) short bf16x8;
typedef __attribute__((ext_vector_type(4))) float f32x4;

__constant__ int c_par[23] = {0,0,0,1,2,3,4,5,6,7,8,9,9,9,12,13,14,16,17,18,19,20,21};

static __device__ __forceinline__ unsigned short f2bf(float f) {
    unsigned int u = __float_as_uint(f);
    unsigned int r = (u + 0x7fffu + ((u >> 16) & 1u)) >> 16;
    return (unsigned short)r;
}
static __device__ __forceinline__ float bf2f(unsigned int u16) {
    return __uint_as_float(u16 << 16);
}

// ws layout:
//   floats: partial[6336] @0, JS[720] @6336, Jt[72] @7056  (end 7128)
//   ushort region @ float ofs 7128:
//     Amat [1024*224]       @0
//     Bmat [20736*224]      @229376
//     Gbf  [1024][16][32]   @4874240   (A-frag-ready transposed, zero-padded)
//     Wbf  [6912][32]       @5398528   (zero-padded)
#define WS_PARTIAL 0
#define WS_JS      6336
#define WS_JT      7056
#define WS_USHORT  7128
#define U_AMAT 0
#define U_BMAT 229376
#define U_GBF  4874240
#define U_WBF  5398528

// ---------------- Kernel 1a: partial reduction for J_regressor ----------------
__global__ void k_jreg_partial(const float* __restrict__ Jreg,
                               const float* __restrict__ shapedirs,
                               const float* __restrict__ v_template,
                               float* __restrict__ partial) {
    const int j = blockIdx.x, chunk = blockIdx.y, tid = threadIdx.x;
    const int per = (N_V + 7) / 8;
    const int v0 = chunk * per;
    const int v1 = (v0 + per < N_V) ? (v0 + per) : N_V;
    float acc[33];
#pragma unroll
    for (int k = 0; k < 33; ++k) acc[k] = 0.f;
    for (int v = v0 + tid; v < v1; v += 256) {
        const float w = Jreg[j * N_V + v];
        const float* sd = shapedirs + (size_t)v * 30;
#pragma unroll
        for (int k = 0; k < 30; ++k) acc[k] += w * sd[k];
        acc[30] += w * v_template[v * 3 + 0];
        acc[31] += w * v_template[v * 3 + 1];
        acc[32] += w * v_template[v * 3 + 2];
    }
#pragma unroll
    for (int k = 0; k < 33; ++k) {
        float x = acc[k];
        for (int off = 32; off > 0; off >>= 1) x += __shfl_down(x, off);
        acc[k] = x;
    }
    __shared__ float red[4][33];
    const int wave = tid >> 6, lane = tid & 63;
    if (lane == 0) {
#pragma unroll
        for (int k = 0; k < 33; ++k) red[wave][k] = acc[k];
    }
    __syncthreads();
    if (tid < 33) {
        partial[(j * 8 + chunk) * 33 + tid] =
            red[0][tid] + red[1][tid] + red[2][tid] + red[3][tid];
    }
}

__global__ void k_jreg_final(const float* __restrict__ partial,
                             float* __restrict__ JS, float* __restrict__ Jt) {
    const int j = blockIdx.x, k = threadIdx.x;
    if (k < 33) {
        float s = 0.f;
#pragma unroll
        for (int c = 0; c < 8; ++c) s += partial[(j * 8 + c) * 33 + k];
        if (k < 30) JS[j * 30 + k] = s;
        else        Jt[j * 3 + (k - 30)] = s;
    }
}

// ---------------- Kernel 2: Bmat = [posedirs | shapedirs | v_template | 0] bf16 ----------------
static __device__ __forceinline__ float bval(const float* pd, const float* sd,
                                             const float* vt, int n, int k) {
    if (n >= NREAL) return 0.f;
    if (k < 207)  return pd[(size_t)n * 207 + k];
    if (k < 217)  return sd[(size_t)n * 10 + (k - 207)];
    if (k == 217) return vt[n];
    return 0.f;
}

__global__ void k_bmat(const float* __restrict__ posedirs,
                       const float* __restrict__ shapedirs,
                       const float* __restrict__ v_template,
                       unsigned short* __restrict__ Bmat) {
    const int n = blockIdx.x;
    const int t = threadIdx.x;  // 128, covers k = 2t, 2t+1
    if (2 * t >= KDIM) return;
    ushort2 o;
    o.x = f2bf(bval(posedirs, shapedirs, v_template, n, 2 * t));
    o.y = f2bf(bval(posedirs, shapedirs, v_template, n, 2 * t + 1));
    *(ushort2*)&Bmat[(size_t)n * KDIM + 2 * t] = o;
}

// ---------------- Kernel 2b: Wbf[v][32] bf16 zero-padded ----------------
__global__ void k_wbf(const float* __restrict__ weights, unsigned short* __restrict__ Wbf) {
    const int idx = blockIdx.x * 256 + threadIdx.x;
    if (idx >= NVPAD * 32) return;
    const int v = idx >> 5, k = idx & 31;
    float val = (v < N_V && k < 24) ? weights[(size_t)v * 24 + k] : 0.f;
    Wbf[idx] = f2bf(val);
}

// ---------------- Kernel 3: per-batch joints: Rodrigues + FK + Amat + Gbf ----------------
__global__ void k_joints(const float* __restrict__ pose, const float* __restrict__ beta,
                         const float* __restrict__ JS, const float* __restrict__ Jt,
                         unsigned short* __restrict__ Amat,
                         unsigned short* __restrict__ Gbf) {
    const int b = blockIdx.x;
    const int j = threadIdx.x;  // 64 threads
    __shared__ float sJ[24][3];
    __shared__ float sG[24][12];

    // zero-fill ONLY the pad entries of Gbf (no overlap with real writes below)
    for (int idx = j; idx < 224; idx += 64) {
        int mn, jj;
        if (idx < 128) { mn = 12 + (idx >> 5); jj = idx & 31; }
        else { const int q = idx - 128; mn = q >> 3; jj = 24 + (q & 7); }
        Gbf[(size_t)b * 512 + mn * 32 + jj] = 0;
    }

    float R[9];
    if (j < 24) {
        const float* bt = beta + b * 10;
#pragma unroll
        for (int c = 0; c < 3; ++c) {
            float s = Jt[j * 3 + c];
#pragma unroll
            for (int t = 0; t < 10; ++t) s += JS[j * 30 + c * 10 + t] * bt[t];
            sJ[j][c] = s;
        }
        const float rx = pose[b * 72 + 3 * j + 0];
        const float ry = pose[b * 72 + 3 * j + 1];
        const float rz = pose[b * 72 + 3 * j + 2];
        const float ang = sqrtf(rx * rx + ry * ry + rz * rz + 1e-8f);
        const float inv = 1.f / ang;
        const float x = rx * inv, y = ry * inv, z = rz * inv;
        const float c = cosf(ang), s = sinf(ang);
        const float ic = 1.f - c;
        R[0] = c + ic * x * x;     R[1] = ic * x * y - s * z; R[2] = ic * x * z + s * y;
        R[3] = ic * x * y + s * z; R[4] = c + ic * y * y;     R[5] = ic * y * z - s * x;
        R[6] = ic * x * z - s * y; R[7] = ic * y * z + s * x; R[8] = c + ic * z * z;
        if (j >= 1) {
            unsigned short* ar = Amat + (size_t)b * KDIM + (j - 1) * 9;
#pragma unroll
            for (int k = 0; k < 9; ++k)
                ar[k] = f2bf(R[k] - ((k == 0 || k == 4 || k == 8) ? 1.f : 0.f));
        }
    } else if (j < 41) {
        const int k = 207 + (j - 24);
        float val = (k < 217) ? beta[b * 10 + (k - 207)] : (k == 217 ? 1.f : 0.f);
        Amat[(size_t)b * KDIM + k] = f2bf(val);
    }
    __syncthreads();
    if (j < 24) {
        float t0, t1, t2;
        if (j == 0) { t0 = sJ[0][0]; t1 = sJ[0][1]; t2 = sJ[0][2]; }
        else {
            const int p = c_par[j - 1];
            t0 = sJ[j][0] - sJ[p][0]; t1 = sJ[j][1] - sJ[p][1]; t2 = sJ[j][2] - sJ[p][2];
        }
        sG[j][0] = R[0]; sG[j][1] = R[1]; sG[j][2]  = R[2]; sG[j][3]  = t0;
        sG[j][4] = R[3]; sG[j][5] = R[4]; sG[j][6]  = R[5]; sG[j][7]  = t1;
        sG[j][8] = R[6]; sG[j][9] = R[7]; sG[j][10] = R[8]; sG[j][11] = t2;
    }
    __syncthreads();
    if (j == 0) {
        for (int i = 1; i < 24; ++i) {
            const int p = c_par[i - 1];
            float P[12], L[12];
#pragma unroll
            for (int k = 0; k < 12; ++k) { P[k] = sG[p][k]; L[k] = sG[i][k]; }
#pragma unroll
            for (int m = 0; m < 3; ++m) {
#pragma unroll
                for (int n = 0; n < 3; ++n)
                    sG[i][m * 4 + n] = P[m * 4] * L[n] + P[m * 4 + 1] * L[4 + n] + P[m * 4 + 2] * L[8 + n];
                sG[i][m * 4 + 3] = P[m * 4] * L[3] + P[m * 4 + 1] * L[7] + P[m * 4 + 2] * L[11] + P[m * 4 + 3];
            }
        }
    }
    __syncthreads();
    if (j < 24) {
        const float jx = sJ[j][0], jy = sJ[j][1], jz = sJ[j][2];
#pragma unroll
        for (int m = 0; m < 3; ++m) {
            const float corr = sG[j][m * 4] * jx + sG[j][m * 4 + 1] * jy + sG[j][m * 4 + 2] * jz;
            Gbf[(size_t)b * 512 + (m * 4 + 0) * 32 + j] = f2bf(sG[j][m * 4 + 0]);
            Gbf[(size_t)b * 512 + (m * 4 + 1) * 32 + j] = f2bf(sG[j][m * 4 + 1]);
            Gbf[(size_t)b * 512 + (m * 4 + 2) * 32 + j] = f2bf(sG[j][m * 4 + 2]);
            Gbf[(size_t)b * 512 + (m * 4 + 3) * 32 + j] = f2bf(sG[j][m * 4 + 3] - corr);
        }
    }
}

// ---------------- Kernel 4: fused pose-GEMM + skinning ----------------
// Block = 128 batches x 32 vertices (96 GEMM columns).
// Phase 1: C[b][n] = Amat[b][:] . Bmat[n][:] -> sH[b][v][c] bf16 (v_posed tile in LDS)
// Phase 2: per b: T = Gbf[b](16x32) x Wbf^T -> lane(v=l&15, m=l>>4) holds T[m][0..3];
//          out[b][v*3+m] = T.(x,y,z,1).
__global__ __launch_bounds__(256)
void k_fused(const unsigned short* __restrict__ Amat,
             const unsigned short* __restrict__ Bmat,
             const unsigned short* __restrict__ Gbf,
             const unsigned short* __restrict__ Wbf,
             float* __restrict__ out) {
    __shared__ unsigned short sA[FB * BK];       // 8 KB
    __shared__ unsigned short sB[96 * BK];       // 6 KB
    __shared__ unsigned short sH[FB * FV * 4];   // 32 KB: [b][v][4]
    const int tid = threadIdx.x;
    const int wid = tid >> 6, l = tid & 63;
    const int c16 = l & 15, p = l >> 4;
    const int v0 = blockIdx.x * FV;
    const int n0 = blockIdx.x * 96;
    const int b0 = blockIdx.y * FB;

    f32x4 acc[2][6];
#pragma unroll
    for (int mi = 0; mi < 2; ++mi)
#pragma unroll
        for (int nf = 0; nf < 6; ++nf) acc[mi][nf] = (f32x4){0.f, 0.f, 0.f, 0.f};

    // ---- phase 1: GEMM 128x96, K=224 ----
    for (int ks = 0; ks < KDIM / BK; ++ks) {
        const int kbase = ks * BK;
        bf16x8 ra[2], rb[2];
#pragma unroll
        for (int i = 0; i < 2; ++i) {
            const int c = tid + 256 * i;
            const int row = c >> 2, u = c & 3;
            ra[i] = *(const bf16x8*)&Amat[(size_t)(b0 + row) * KDIM + kbase + u * 8];
            if (i == 0 || row < 96)
                rb[i] = *(const bf16x8*)&Bmat[(size_t)(n0 + (row < 96 ? row : 0)) * KDIM + kbase + u * 8];
        }
        __syncthreads();
#pragma unroll
        for (int i = 0; i < 2; ++i) {
            const int c = tid + 256 * i;
            const int row = c >> 2, u = c & 3;
            *(bf16x8*)&sA[row * BK + u * 8] = ra[i];
            if (row < 96) *(bf16x8*)&sB[row * BK + u * 8] = rb[i];
        }
        __syncthreads();

        bf16x8 af[2], bfr[6];
#pragma unroll
        for (int mi = 0; mi < 2; ++mi)
            af[mi] = *(const bf16x8*)&sA[(wid * 32 + mi * 16 + c16) * BK + p * 8];
#pragma unroll
        for (int nf = 0; nf < 6; ++nf)
            bfr[nf] = *(const bf16x8*)&sB[(nf * 16 + c16) * BK + p * 8];
#pragma unroll
        for (int mi = 0; mi < 2; ++mi)
#pragma unroll
            for (int nf = 0; nf < 6; ++nf)
                acc[mi][nf] = __builtin_amdgcn_mfma_f32_16x16x32_bf16(af[mi], bfr[nf], acc[mi][nf], 0, 0, 0);
    }

    // ---- epilogue: C tile -> sH bf16 ----
    __syncthreads();  // sA/sB reads done before sH overwrites nothing, but keep phase edge clean
#pragma unroll
    for (int mi = 0; mi < 2; ++mi) {
#pragma unroll
        for (int nf = 0; nf < 6; ++nf) {
            const int nc = nf * 16 + c16;
            const int vl = nc / 3;            // magic-mul
            const int cc = nc - vl * 3;
#pragma unroll
            for (int r = 0; r < 4; ++r) {
                const int bl = wid * 32 + mi * 16 + p * 4 + r;
                sH[bl * (FV * 4) + vl * 4 + cc] = f2bf(acc[mi][nf][r]);
            }
        }
    }
    __syncthreads();

    // ---- phase 2: per-b skinning MFMA ----
    const bf16x8 bw0 = *(const bf16x8*)&Wbf[(size_t)(v0 + c16) * 32 + p * 8];
    const bf16x8 bw1 = *(const bf16x8*)&Wbf[(size_t)(v0 + 16 + c16) * 32 + p * 8];
    const int agofs = c16 * 32 + p * 8;

    bf16x8 ag = *(const bf16x8*)&Gbf[(size_t)(b0 + wid * 32) * 512 + agofs];
    for (int i = 0; i < 32; ++i) {
        const int bl = wid * 32 + i;
        bf16x8 agn = ag;
        if (i < 31)
            agn = *(const bf16x8*)&Gbf[(size_t)(b0 + bl + 1) * 512 + agofs];

        const f32x4 t0 = __builtin_amdgcn_mfma_f32_16x16x32_bf16(ag, bw0, (f32x4){0.f,0.f,0.f,0.f}, 0, 0, 0);
        const f32x4 t1 = __builtin_amdgcn_mfma_f32_16x16x32_bf16(ag, bw1, (f32x4){0.f,0.f,0.f,0.f}, 0, 0, 0);

#pragma unroll
        for (int g = 0; g < 2; ++g) {
            const int vl = c16 + g * 16;
            const uint2 h = *(const uint2*)&sH[bl * (FV * 4) + vl * 4];
            const float x = bf2f(h.x & 0xffffu);
            const float y = bf2f(h.x >> 16);
            const float z = bf2f(h.y & 0xffffu);
            const f32x4 T = g ? t1 : t0;
            const float r = T[0] * x + T[1] * y + T[2] * z + T[3];
            if (v0 + vl < N_V && p < 3)
                out[(size_t)(b0 + bl) * NREAL + (v0 + vl) * 3 + p] = r;
        }
        ag = agn;
    }
}

extern "C" void kernel_launch(void* const* d_in, const int* in_sizes, int n_in,
                              void* d_out, int out_size, void* d_ws, size_t ws_size,
                              hipStream_t stream) {
    const float* pose       = (const float*)d_in[0];
    const float* beta       = (const float*)d_in[1];
    const float* shapedirs  = (const float*)d_in[2];
    const float* posedirs   = (const float*)d_in[3];
    const float* v_template = (const float*)d_in[4];
    const float* Jreg       = (const float*)d_in[5];
    const float* weights    = (const float*)d_in[6];
    float* out = (float*)d_out;

    const int B = in_sizes[0] / 72;  // 1024

    float* ws      = (float*)d_ws;
    float* partial = ws + WS_PARTIAL;
    float* JS      = ws + WS_JS;
    float* Jt      = ws + WS_JT;
    unsigned short* ubase = (unsigned short*)(ws + WS_USHORT);
    unsigned short* Amat = ubase + U_AMAT;
    unsigned short* Bmat = ubase + U_BMAT;
    unsigned short* Gbf  = ubase + U_GBF;
    unsigned short* Wbf  = ubase + U_WBF;

    k_jreg_partial<<<dim3(24, 8), 256, 0, stream>>>(Jreg, shapedirs, v_template, partial);
    k_jreg_final<<<24, 64, 0, stream>>>(partial, JS, Jt);
    k_bmat<<<NPAD, 128, 0, stream>>>(posedirs, shapedirs, v_template, Bmat);
    k_wbf<<<(NVPAD * 32 + 255) / 256, 256, 0, stream>>>(weights, Wbf);
    k_joints<<<B, 64, 0, stream>>>(pose, beta, JS, Jt, Amat, Gbf);
    k_fused<<<dim3(NVPAD / FV, B / FB), 256, 0, stream>>>(Amat, Bmat, Gbf, Wbf, out);
}

// Round 6
// 95.727 us; speedup vs baseline: 10.0758x; 1.0524x over previous
//
#include <hip/hip_runtime.h>
#include <hip/hip_bf16.h>

#define N_V 6890
#define NVPAD 6912    // padded vertex count (216*32)
#define N_J 24
#define NREAL 20670   // N_V*3
#define NPROWS 27648  // NVPAD*4 padded GEMM rows (n' = 4v+c, c=3 dummy)
#define KDIM 224      // 207 lrot + 10 beta + 1 template + 6 zero pad
#define BK 32
#define FB 128        // batches per fused block
#define FV 32         // vertices per fused block -> NP = 128 rows
#define NP 128
#define SAP 40        // LDS pitch (ushorts) for operand tiles (80B, 16B-aligned frags)
#define SHP 132       // LDS pitch (ushorts) for sH (264B, 8B-aligned slots, 66w%32=2)

typedef __attribute__((ext_vector_type(8))) short bf16x8;
typedef __attribute__((ext_vector_type(4))) float f32x4;

__constant__ int c_par[23] = {0,0,0,1,2,3,4,5,6,7,8,9,9,9,12,13,14,16,17,18,19,20,21};

static __device__ __forceinline__ unsigned short f2bf(float f) {
    unsigned int u = __float_as_uint(f);
    unsigned int r = (u + 0x7fffu + ((u >> 16) & 1u)) >> 16;
    return (unsigned short)r;
}
// fast pack: round-half-up (bias <= 0.5 ulp, fine at our tolerance)
static __device__ __forceinline__ unsigned int pkbf(float a, float b) {
    return ((__float_as_uint(a) + 0x8000u) >> 16) |
           ((__float_as_uint(b) + 0x8000u) & 0xffff0000u);
}

// ws layout:
//   floats: partial[6336] @0, JS[720] @6336, Jt[72] @7056  (end 7128)
//   ushort region @ float ofs 7128:
//     Amat [1024*224]        @0
//     Bp   [27648*224]       @229376
//     Gbf  [1024][16][32]    @6422528
//     Wbf  [6912][32]        @6946816   (end 7168000 ushorts = 14.3 MB)
#define WS_PARTIAL 0
#define WS_JS      6336
#define WS_JT      7056
#define WS_USHORT  7128
#define U_AMAT 0
#define U_BP   229376
#define U_GBF  6422528
#define U_WBF  6946816

// ---------------- Kernel 1a: partial reduction for J_regressor ----------------
__global__ void k_jreg_partial(const float* __restrict__ Jreg,
                               const float* __restrict__ shapedirs,
                               const float* __restrict__ v_template,
                               float* __restrict__ partial) {
    const int j = blockIdx.x, chunk = blockIdx.y, tid = threadIdx.x;
    const int per = (N_V + 7) / 8;
    const int v0 = chunk * per;
    const int v1 = (v0 + per < N_V) ? (v0 + per) : N_V;
    float acc[33];
#pragma unroll
    for (int k = 0; k < 33; ++k) acc[k] = 0.f;
    for (int v = v0 + tid; v < v1; v += 256) {
        const float w = Jreg[j * N_V + v];
        const float* sd = shapedirs + (size_t)v * 30;
#pragma unroll
        for (int k = 0; k < 30; ++k) acc[k] += w * sd[k];
        acc[30] += w * v_template[v * 3 + 0];
        acc[31] += w * v_template[v * 3 + 1];
        acc[32] += w * v_template[v * 3 + 2];
    }
#pragma unroll
    for (int k = 0; k < 33; ++k) {
        float x = acc[k];
        for (int off = 32; off > 0; off >>= 1) x += __shfl_down(x, off);
        acc[k] = x;
    }
    __shared__ float red[4][33];
    const int wave = tid >> 6, lane = tid & 63;
    if (lane == 0) {
#pragma unroll
        for (int k = 0; k < 33; ++k) red[wave][k] = acc[k];
    }
    __syncthreads();
    if (tid < 33) {
        partial[(j * 8 + chunk) * 33 + tid] =
            red[0][tid] + red[1][tid] + red[2][tid] + red[3][tid];
    }
}

__global__ void k_jreg_final(const float* __restrict__ partial,
                             float* __restrict__ JS, float* __restrict__ Jt) {
    const int j = blockIdx.x, k = threadIdx.x;
    if (k < 33) {
        float s = 0.f;
#pragma unroll
        for (int c = 0; c < 8; ++c) s += partial[(j * 8 + c) * 33 + k];
        if (k < 30) JS[j * 30 + k] = s;
        else        Jt[j * 3 + (k - 30)] = s;
    }
}

// ---------------- Kernel 2: Bp[n'=4v+c][k] bf16 (c=3 dummy zero row) ----------------
static __device__ __forceinline__ float bval(const float* pd, const float* sd,
                                             const float* vt, int nc, int k) {
    if (k < 207)  return pd[(size_t)nc * 207 + k];
    if (k < 217)  return sd[(size_t)nc * 10 + (k - 207)];
    if (k == 217) return vt[nc];
    return 0.f;
}

__global__ void k_bp(const float* __restrict__ posedirs,
                     const float* __restrict__ shapedirs,
                     const float* __restrict__ v_template,
                     unsigned short* __restrict__ Bp) {
    const int np = blockIdx.x;   // 0..27647
    const int t = threadIdx.x;   // 128
    const int k = 2 * t;
    if (k >= KDIM) return;
    const int v = np >> 2, cc = np & 3;
    float a = 0.f, b = 0.f;
    if (cc < 3 && v < N_V) {
        const int nc = v * 3 + cc;
        a = bval(posedirs, shapedirs, v_template, nc, k);
        b = bval(posedirs, shapedirs, v_template, nc, k + 1);
    }
    ushort2 o; o.x = f2bf(a); o.y = f2bf(b);
    *(ushort2*)&Bp[(size_t)np * KDIM + k] = o;
}

// ---------------- Kernel 2b: Wbf[v][32] bf16 zero-padded ----------------
__global__ void k_wbf(const float* __restrict__ weights, unsigned short* __restrict__ Wbf) {
    const int idx = blockIdx.x * 256 + threadIdx.x;
    if (idx >= NVPAD * 32) return;
    const int v = idx >> 5, k = idx & 31;
    float val = (v < N_V && k < 24) ? weights[(size_t)v * 24 + k] : 0.f;
    Wbf[idx] = f2bf(val);
}

// ---------------- Kernel 3: per-batch joints: Rodrigues + FK + Amat + Gbf ----------------
__global__ void k_joints(const float* __restrict__ pose, const float* __restrict__ beta,
                         const float* __restrict__ JS, const float* __restrict__ Jt,
                         unsigned short* __restrict__ Amat,
                         unsigned short* __restrict__ Gbf) {
    const int b = blockIdx.x;
    const int j = threadIdx.x;  // 64 threads
    __shared__ float sJ[24][3];
    __shared__ float sG[24][12];

    // zero-fill ONLY the pad entries of Gbf
    for (int idx = j; idx < 224; idx += 64) {
        int mn, jj;
        if (idx < 128) { mn = 12 + (idx >> 5); jj = idx & 31; }
        else { const int q = idx - 128; mn = q >> 3; jj = 24 + (q & 7); }
        Gbf[(size_t)b * 512 + mn * 32 + jj] = 0;
    }

    float R[9];
    if (j < 24) {
        const float* bt = beta + b * 10;
#pragma unroll
        for (int c = 0; c < 3; ++c) {
            float s = Jt[j * 3 + c];
#pragma unroll
            for (int t = 0; t < 10; ++t) s += JS[j * 30 + c * 10 + t] * bt[t];
            sJ[j][c] = s;
        }
        const float rx = pose[b * 72 + 3 * j + 0];
        const float ry = pose[b * 72 + 3 * j + 1];
        const float rz = pose[b * 72 + 3 * j + 2];
        const float ang = sqrtf(rx * rx + ry * ry + rz * rz + 1e-8f);
        const float inv = 1.f / ang;
        const float x = rx * inv, y = ry * inv, z = rz * inv;
        const float c = cosf(ang), s = sinf(ang);
        const float ic = 1.f - c;
        R[0] = c + ic * x * x;     R[1] = ic * x * y - s * z; R[2] = ic * x * z + s * y;
        R[3] = ic * x * y + s * z; R[4] = c + ic * y * y;     R[5] = ic * y * z - s * x;
        R[6] = ic * x * z - s * y; R[7] = ic * y * z + s * x; R[8] = c + ic * z * z;
        if (j >= 1) {
            unsigned short* ar = Amat + (size_t)b * KDIM + (j - 1) * 9;
#pragma unroll
            for (int k = 0; k < 9; ++k)
                ar[k] = f2bf(R[k] - ((k == 0 || k == 4 || k == 8) ? 1.f : 0.f));
        }
    } else if (j < 41) {
        const int k = 207 + (j - 24);
        float val = (k < 217) ? beta[b * 10 + (k - 207)] : (k == 217 ? 1.f : 0.f);
        Amat[(size_t)b * KDIM + k] = f2bf(val);
    }
    __syncthreads();
    if (j < 24) {
        float t0, t1, t2;
        if (j == 0) { t0 = sJ[0][0]; t1 = sJ[0][1]; t2 = sJ[0][2]; }
        else {
            const int p = c_par[j - 1];
            t0 = sJ[j][0] - sJ[p][0]; t1 = sJ[j][1] - sJ[p][1]; t2 = sJ[j][2] - sJ[p][2];
        }
        sG[j][0] = R[0]; sG[j][1] = R[1]; sG[j][2]  = R[2]; sG[j][3]  = t0;
        sG[j][4] = R[3]; sG[j][5] = R[4]; sG[j][6]  = R[5]; sG[j][7]  = t1;
        sG[j][8] = R[6]; sG[j][9] = R[7]; sG[j][10] = R[8]; sG[j][11] = t2;
    }
    __syncthreads();
    if (j == 0) {
        for (int i = 1; i < 24; ++i) {
            const int p = c_par[i - 1];
            float P[12], L[12];
#pragma unroll
            for (int k = 0; k < 12; ++k) { P[k] = sG[p][k]; L[k] = sG[i][k]; }
#pragma unroll
            for (int m = 0; m < 3; ++m) {
#pragma unroll
                for (int n = 0; n < 3; ++n)
                    sG[i][m * 4 + n] = P[m * 4] * L[n] + P[m * 4 + 1] * L[4 + n] + P[m * 4 + 2] * L[8 + n];
                sG[i][m * 4 + 3] = P[m * 4] * L[3] + P[m * 4 + 1] * L[7] + P[m * 4 + 2] * L[11] + P[m * 4 + 3];
            }
        }
    }
    __syncthreads();
    if (j < 24) {
        const float jx = sJ[j][0], jy = sJ[j][1], jz = sJ[j][2];
#pragma unroll
        for (int m = 0; m < 3; ++m) {
            const float corr = sG[j][m * 4] * jx + sG[j][m * 4 + 1] * jy + sG[j][m * 4 + 2] * jz;
            Gbf[(size_t)b * 512 + (m * 4 + 0) * 32 + j] = f2bf(sG[j][m * 4 + 0]);
            Gbf[(size_t)b * 512 + (m * 4 + 1) * 32 + j] = f2bf(sG[j][m * 4 + 1]);
            Gbf[(size_t)b * 512 + (m * 4 + 2) * 32 + j] = f2bf(sG[j][m * 4 + 2]);
            Gbf[(size_t)b * 512 + (m * 4 + 3) * 32 + j] = f2bf(sG[j][m * 4 + 3] - corr);
        }
    }
}

// ---------------- Kernel 4: fused transposed pose-GEMM + skinning ----------------
// Phase 1: C[n'][b] = Bp[n'][:] . Amat[b][:], tile 128 n' x 128 b, K=224.
//   Lane (c16,p), wave (wr,wc): acc[mi][bj][r] = C[wr+mi*16+p*4+r][wc+bj*16+c16]
//   -> 4 consecutive n' = one vertex slot -> one ds_write_b64 to sH[b][v][4].
// Phase 2: per batch bl: T = Gbf[b](16x32) x Wbf^T(32x16); lane (v=c16,m=p)
//   holds T[m][0..3]; out = T.(x,y,z,1) with h from sH.
__global__ __launch_bounds__(256)
void k_fused(const unsigned short* __restrict__ Amat,
             const unsigned short* __restrict__ Bp,
             const unsigned short* __restrict__ Gbf,
             const unsigned short* __restrict__ Wbf,
             float* __restrict__ out) {
    __shared__ unsigned short sN[NP * SAP];   // 10,240 B  (Bp rows)
    __shared__ unsigned short sM[FB * SAP];   // 10,240 B  (Amat rows)
    __shared__ unsigned short sH[FB * SHP];   // 33,792 B  ([b][v][4] bf16)
    const int tid = threadIdx.x;
    const int wid = tid >> 6, l = tid & 63;
    const int c16 = l & 15, p = l >> 4;
    const int wr = (wid >> 1) * 64;   // n' base of wave
    const int wc = (wid & 1) * 64;    // b  base of wave
    const int n0 = blockIdx.x * NP;
    const int v0 = blockIdx.x * FV;
    const int b0 = blockIdx.y * FB;

    // -------- phase 1 --------
    f32x4 acc[4][4];
#pragma unroll
    for (int i = 0; i < 4; ++i)
#pragma unroll
        for (int j = 0; j < 4; ++j) acc[i][j] = (f32x4){0.f, 0.f, 0.f, 0.f};

    // staging: thread -> rows (srow, srow+64), k-chunk su
    const int srow = tid >> 2;
    const int su = (tid & 3) * 8;
    const unsigned short* gN = Bp + (size_t)(n0 + srow) * KDIM + su;
    const unsigned short* gM = Amat + (size_t)(b0 + srow) * KDIM + su;
    unsigned short* wN = &sN[srow * SAP + su];
    unsigned short* wM = &sM[srow * SAP + su];

    bf16x8 rN0 = *(const bf16x8*)gN;
    bf16x8 rN1 = *(const bf16x8*)(gN + 64 * KDIM);
    bf16x8 rM0 = *(const bf16x8*)gM;
    bf16x8 rM1 = *(const bf16x8*)(gM + 64 * KDIM);

    for (int ks = 0; ks < KDIM / BK; ++ks) {
        __syncthreads();
        *(bf16x8*)wN = rN0; *(bf16x8*)(wN + 64 * SAP) = rN1;
        *(bf16x8*)wM = rM0; *(bf16x8*)(wM + 64 * SAP) = rM1;
        if (ks < KDIM / BK - 1) {  // prefetch next K-step (hidden under MFMA below)
            gN += BK; gM += BK;
            rN0 = *(const bf16x8*)gN;
            rN1 = *(const bf16x8*)(gN + 64 * KDIM);
            rM0 = *(const bf16x8*)gM;
            rM1 = *(const bf16x8*)(gM + 64 * KDIM);
        }
        __syncthreads();

        bf16x8 af[4], bfr[4];
#pragma unroll
        for (int mi = 0; mi < 4; ++mi)
            af[mi] = *(const bf16x8*)&sN[(wr + mi * 16 + c16) * SAP + p * 8];
#pragma unroll
        for (int bj = 0; bj < 4; ++bj)
            bfr[bj] = *(const bf16x8*)&sM[(wc + bj * 16 + c16) * SAP + p * 8];
#pragma unroll
        for (int mi = 0; mi < 4; ++mi)
#pragma unroll
            for (int bj = 0; bj < 4; ++bj)
                acc[mi][bj] = __builtin_amdgcn_mfma_f32_16x16x32_bf16(af[mi], bfr[bj], acc[mi][bj], 0, 0, 0);
    }

    // -------- epilogue: acc -> sH (b64 per vertex slot) --------
    __syncthreads();
    {
        const int wrq = (wr >> 2);  // vl base
#pragma unroll
        for (int mi = 0; mi < 4; ++mi) {
#pragma unroll
            for (int bj = 0; bj < 4; ++bj) {
                const int vl = wrq + mi * 4 + p;
                const int bl = wc + bj * 16 + c16;
                uint2 u;
                u.x = pkbf(acc[mi][bj][0], acc[mi][bj][1]);
                u.y = pkbf(acc[mi][bj][2], acc[mi][bj][3]);
                *(uint2*)&sH[bl * SHP + vl * 4] = u;
            }
        }
    }
    __syncthreads();

    // -------- phase 2: skinning --------
    const bf16x8 bw0 = *(const bf16x8*)&Wbf[(size_t)(v0 + c16) * 32 + p * 8];
    const bf16x8 bw1 = *(const bf16x8*)&Wbf[(size_t)(v0 + 16 + c16) * 32 + p * 8];
    const bool st0 = (v0 + c16 < N_V) && (p < 3);
    const bool st1 = (v0 + 16 + c16 < N_V) && (p < 3);
    const int bwv = wid * 32;  // wave's local batch base
    const unsigned short* gG = Gbf + (size_t)(b0 + bwv) * 512 + c16 * 32 + p * 8;
    const unsigned short* sh = &sH[bwv * SHP + c16 * 4];
    float* o0 = out + (size_t)(b0 + bwv) * NREAL + (size_t)(v0 + c16) * 3 + p;
    float* o1 = o0 + 48;  // vertex +16 -> +48 floats

    for (int ii = 0; ii < 32; ii += 8) {
        bf16x8 ag[8];
#pragma unroll
        for (int j = 0; j < 8; ++j)
            ag[j] = *(const bf16x8*)(gG + (size_t)(ii + j) * 512);
#pragma unroll
        for (int j = 0; j < 8; ++j) {
            const f32x4 t0 = __builtin_amdgcn_mfma_f32_16x16x32_bf16(ag[j], bw0, (f32x4){0.f,0.f,0.f,0.f}, 0, 0, 0);
            const f32x4 t1 = __builtin_amdgcn_mfma_f32_16x16x32_bf16(ag[j], bw1, (f32x4){0.f,0.f,0.f,0.f}, 0, 0, 0);
            const uint2 h0 = *(const uint2*)(sh + (ii + j) * SHP);
            const uint2 h1 = *(const uint2*)(sh + (ii + j) * SHP + 64);
            const float x0 = __uint_as_float(h0.x << 16);
            const float y0 = __uint_as_float(h0.x & 0xffff0000u);
            const float z0 = __uint_as_float(h0.y << 16);
            const float x1 = __uint_as_float(h1.x << 16);
            const float y1 = __uint_as_float(h1.x & 0xffff0000u);
            const float z1 = __uint_as_float(h1.y << 16);
            const float r0 = t0[0] * x0 + t0[1] * y0 + t0[2] * z0 + t0[3];
            const float r1 = t1[0] * x1 + t1[1] * y1 + t1[2] * z1 + t1[3];
            if (st0) o0[(size_t)(ii + j) * NREAL] = r0;
            if (st1) o1[(size_t)(ii + j) * NREAL] = r1;
        }
    }
}

extern "C" void kernel_launch(void* const* d_in, const int* in_sizes, int n_in,
                              void* d_out, int out_size, void* d_ws, size_t ws_size,
                              hipStream_t stream) {
    const float* pose       = (const float*)d_in[0];
    const float* beta       = (const float*)d_in[1];
    const float* shapedirs  = (const float*)d_in[2];
    const float* posedirs   = (const float*)d_in[3];
    const float* v_template = (const float*)d_in[4];
    const float* Jreg       = (const float*)d_in[5];
    const float* weights    = (const float*)d_in[6];
    float* out = (float*)d_out;

    const int B = in_sizes[0] / 72;  // 1024

    float* ws      = (float*)d_ws;
    float* partial = ws + WS_PARTIAL;
    float* JS      = ws + WS_JS;
    float* Jt      = ws + WS_JT;
    unsigned short* ubase = (unsigned short*)(ws + WS_USHORT);
    unsigned short* Amat = ubase + U_AMAT;
    unsigned short* Bp   = ubase + U_BP;
    unsigned short* Gbf  = ubase + U_GBF;
    unsigned short* Wbf  = ubase + U_WBF;

    k_jreg_partial<<<dim3(24, 8), 256, 0, stream>>>(Jreg, shapedirs, v_template, partial);
    k_jreg_final<<<24, 64, 0, stream>>>(partial, JS, Jt);
    k_bp<<<NPROWS, 128, 0, stream>>>(posedirs, shapedirs, v_template, Bp);
    k_wbf<<<(NVPAD * 32 + 255) / 256, 256, 0, stream>>>(weights, Wbf);
    k_joints<<<B, 64, 0, stream>>>(pose, beta, JS, Jt, Amat, Gbf);
    k_fused<<<dim3(NVPAD / FV, B / FB), 256, 0, stream>>>(Amat, Bp, Gbf, Wbf, out);
}

// Round 7
// 88.363 us; speedup vs baseline: 10.9155x; 1.0833x over previous
//
#include <hip/hip_runtime.h>
#include <hip/hip_bf16.h>

#define N_V 6890
#define NVPAD 6912    // padded vertex count (216*32)
#define N_J 24
#define NREAL 20670   // N_V*3
#define NPROWS 27648  // NVPAD*4 padded GEMM rows (n' = 4v+c, c=3 dummy)
#define KDIM 224      // 207 lrot + 10 beta + 1 template + 6 zero pad
#define BK 32
#define FB 64         // batches per fused block
#define FV 32         // vertices per fused block -> NP = 128 rows
#define NP 128
#define SAP 40        // LDS pitch (ushorts) for operand tiles (80B, 16B-aligned frags)
#define SHP 132       // LDS pitch (ushorts) for sH (264B, 8B slots, 66w%32=2 -> 2-way max)

typedef __attribute__((ext_vector_type(8))) short bf16x8;
typedef __attribute__((ext_vector_type(4))) float f32x4;

__constant__ int c_par[23] = {0,0,0,1,2,3,4,5,6,7,8,9,9,9,12,13,14,16,17,18,19,20,21};

static __device__ __forceinline__ unsigned short f2bf(float f) {
    unsigned int u = __float_as_uint(f);
    unsigned int r = (u + 0x7fffu + ((u >> 16) & 1u)) >> 16;
    return (unsigned short)r;
}
// fast pack: round-half-up (bias <= 0.5 ulp, fine at our tolerance)
static __device__ __forceinline__ unsigned int pkbf(float a, float b) {
    return ((__float_as_uint(a) + 0x8000u) >> 16) |
           ((__float_as_uint(b) + 0x8000u) & 0xffff0000u);
}

// ws layout:
//   floats: partial[6336] @0, JS[720] @6336, Jt[72] @7056  (end 7128)
//   ushort region @ float ofs 7128:
//     Amat [1024*224]        @0
//     Bp   [27648*224]       @229376
//     Gbf  [1024][16][32]    @6422528
//     Wbf  [6912][32]        @6946816
#define WS_PARTIAL 0
#define WS_JS      6336
#define WS_JT      7056
#define WS_USHORT  7128
#define U_AMAT 0
#define U_BP   229376
#define U_GBF  6422528
#define U_WBF  6946816

// ---------------- Kernel 1a: partial reduction for J_regressor ----------------
__global__ void k_jreg_partial(const float* __restrict__ Jreg,
                               const float* __restrict__ shapedirs,
                               const float* __restrict__ v_template,
                               float* __restrict__ partial) {
    const int j = blockIdx.x, chunk = blockIdx.y, tid = threadIdx.x;
    const int per = (N_V + 7) / 8;
    const int v0 = chunk * per;
    const int v1 = (v0 + per < N_V) ? (v0 + per) : N_V;
    float acc[33];
#pragma unroll
    for (int k = 0; k < 33; ++k) acc[k] = 0.f;
    for (int v = v0 + tid; v < v1; v += 256) {
        const float w = Jreg[j * N_V + v];
        const float* sd = shapedirs + (size_t)v * 30;
#pragma unroll
        for (int k = 0; k < 30; ++k) acc[k] += w * sd[k];
        acc[30] += w * v_template[v * 3 + 0];
        acc[31] += w * v_template[v * 3 + 1];
        acc[32] += w * v_template[v * 3 + 2];
    }
#pragma unroll
    for (int k = 0; k < 33; ++k) {
        float x = acc[k];
        for (int off = 32; off > 0; off >>= 1) x += __shfl_down(x, off);
        acc[k] = x;
    }
    __shared__ float red[4][33];
    const int wave = tid >> 6, lane = tid & 63;
    if (lane == 0) {
#pragma unroll
        for (int k = 0; k < 33; ++k) red[wave][k] = acc[k];
    }
    __syncthreads();
    if (tid < 33) {
        partial[(j * 8 + chunk) * 33 + tid] =
            red[0][tid] + red[1][tid] + red[2][tid] + red[3][tid];
    }
}

__global__ void k_jreg_final(const float* __restrict__ partial,
                             float* __restrict__ JS, float* __restrict__ Jt) {
    const int j = blockIdx.x, k = threadIdx.x;
    if (k < 33) {
        float s = 0.f;
#pragma unroll
        for (int c = 0; c < 8; ++c) s += partial[(j * 8 + c) * 33 + k];
        if (k < 30) JS[j * 30 + k] = s;
        else        Jt[j * 3 + (k - 30)] = s;
    }
}

// ---------------- Kernel 2: merged Bp + Wbf prep ----------------
static __device__ __forceinline__ float bval(const float* pd, const float* sd,
                                             const float* vt, int nc, int k) {
    if (k < 207)  return pd[(size_t)nc * 207 + k];
    if (k < 217)  return sd[(size_t)nc * 10 + (k - 207)];
    if (k == 217) return vt[nc];
    return 0.f;
}

#define BP_BLOCKS (NPROWS / 2)          // 13824, two Bp rows per block
#define WBF_BLOCKS (NVPAD * 32 / 256)   // 864

__global__ void k_prep(const float* __restrict__ posedirs,
                       const float* __restrict__ shapedirs,
                       const float* __restrict__ v_template,
                       const float* __restrict__ weights,
                       unsigned short* __restrict__ Bp,
                       unsigned short* __restrict__ Wbf) {
    const int bid = blockIdx.x;
    if (bid < BP_BLOCKS) {
        const int np = bid * 2 + (threadIdx.x >> 7);
        const int t = threadIdx.x & 127;
        const int k = 2 * t;
        if (k >= KDIM) return;
        const int v = np >> 2, cc = np & 3;
        float a = 0.f, b = 0.f;
        if (cc < 3 && v < N_V) {
            const int nc = v * 3 + cc;
            a = bval(posedirs, shapedirs, v_template, nc, k);
            b = bval(posedirs, shapedirs, v_template, nc, k + 1);
        }
        ushort2 o; o.x = f2bf(a); o.y = f2bf(b);
        *(ushort2*)&Bp[(size_t)np * KDIM + k] = o;
    } else {
        const int idx = (bid - BP_BLOCKS) * 256 + threadIdx.x;
        const int v = idx >> 5, k = idx & 31;
        float val = (v < N_V && k < 24) ? weights[(size_t)v * 24 + k] : 0.f;
        Wbf[idx] = f2bf(val);
    }
}

// ---------------- Kernel 3: per-batch joints: Rodrigues + FK + Amat + Gbf ----------------
__global__ void k_joints(const float* __restrict__ pose, const float* __restrict__ beta,
                         const float* __restrict__ JS, const float* __restrict__ Jt,
                         unsigned short* __restrict__ Amat,
                         unsigned short* __restrict__ Gbf) {
    const int b = blockIdx.x;
    const int j = threadIdx.x;  // 64 threads
    __shared__ float sJ[24][3];
    __shared__ float sG[24][12];

    // zero-fill ONLY the pad entries of Gbf
    for (int idx = j; idx < 224; idx += 64) {
        int mn, jj;
        if (idx < 128) { mn = 12 + (idx >> 5); jj = idx & 31; }
        else { const int q = idx - 128; mn = q >> 3; jj = 24 + (q & 7); }
        Gbf[(size_t)b * 512 + mn * 32 + jj] = 0;
    }

    float R[9];
    if (j < 24) {
        const float* bt = beta + b * 10;
#pragma unroll
        for (int c = 0; c < 3; ++c) {
            float s = Jt[j * 3 + c];
#pragma unroll
            for (int t = 0; t < 10; ++t) s += JS[j * 30 + c * 10 + t] * bt[t];
            sJ[j][c] = s;
        }
        const float rx = pose[b * 72 + 3 * j + 0];
        const float ry = pose[b * 72 + 3 * j + 1];
        const float rz = pose[b * 72 + 3 * j + 2];
        const float ang = sqrtf(rx * rx + ry * ry + rz * rz + 1e-8f);
        const float inv = 1.f / ang;
        const float x = rx * inv, y = ry * inv, z = rz * inv;
        const float c = cosf(ang), s = sinf(ang);
        const float ic = 1.f - c;
        R[0] = c + ic * x * x;     R[1] = ic * x * y - s * z; R[2] = ic * x * z + s * y;
        R[3] = ic * x * y + s * z; R[4] = c + ic * y * y;     R[5] = ic * y * z - s * x;
        R[6] = ic * x * z - s * y; R[7] = ic * y * z + s * x; R[8] = c + ic * z * z;
        if (j >= 1) {
            unsigned short* ar = Amat + (size_t)b * KDIM + (j - 1) * 9;
#pragma unroll
            for (int k = 0; k < 9; ++k)
                ar[k] = f2bf(R[k] - ((k == 0 || k == 4 || k == 8) ? 1.f : 0.f));
        }
    } else if (j < 41) {
        const int k = 207 + (j - 24);
        float val = (k < 217) ? beta[b * 10 + (k - 207)] : (k == 217 ? 1.f : 0.f);
        Amat[(size_t)b * KDIM + k] = f2bf(val);
    }
    __syncthreads();
    if (j < 24) {
        float t0, t1, t2;
        if (j == 0) { t0 = sJ[0][0]; t1 = sJ[0][1]; t2 = sJ[0][2]; }
        else {
            const int p = c_par[j - 1];
            t0 = sJ[j][0] - sJ[p][0]; t1 = sJ[j][1] - sJ[p][1]; t2 = sJ[j][2] - sJ[p][2];
        }
        sG[j][0] = R[0]; sG[j][1] = R[1]; sG[j][2]  = R[2]; sG[j][3]  = t0;
        sG[j][4] = R[3]; sG[j][5] = R[4]; sG[j][6]  = R[5]; sG[j][7]  = t1;
        sG[j][8] = R[6]; sG[j][9] = R[7]; sG[j][10] = R[8]; sG[j][11] = t2;
    }
    __syncthreads();
    if (j == 0) {
        for (int i = 1; i < 24; ++i) {
            const int p = c_par[i - 1];
            float P[12], L[12];
#pragma unroll
            for (int k = 0; k < 12; ++k) { P[k] = sG[p][k]; L[k] = sG[i][k]; }
#pragma unroll
            for (int m = 0; m < 3; ++m) {
#pragma unroll
                for (int n = 0; n < 3; ++n)
                    sG[i][m * 4 + n] = P[m * 4] * L[n] + P[m * 4 + 1] * L[4 + n] + P[m * 4 + 2] * L[8 + n];
                sG[i][m * 4 + 3] = P[m * 4] * L[3] + P[m * 4 + 1] * L[7] + P[m * 4 + 2] * L[11] + P[m * 4 + 3];
            }
        }
    }
    __syncthreads();
    if (j < 24) {
        const float jx = sJ[j][0], jy = sJ[j][1], jz = sJ[j][2];
#pragma unroll
        for (int m = 0; m < 3; ++m) {
            const float corr = sG[j][m * 4] * jx + sG[j][m * 4 + 1] * jy + sG[j][m * 4 + 2] * jz;
            Gbf[(size_t)b * 512 + (m * 4 + 0) * 32 + j] = f2bf(sG[j][m * 4 + 0]);
            Gbf[(size_t)b * 512 + (m * 4 + 1) * 32 + j] = f2bf(sG[j][m * 4 + 1]);
            Gbf[(size_t)b * 512 + (m * 4 + 2) * 32 + j] = f2bf(sG[j][m * 4 + 2]);
            Gbf[(size_t)b * 512 + (m * 4 + 3) * 32 + j] = f2bf(sG[j][m * 4 + 3] - corr);
        }
    }
}

// ---------------- Kernel 4: fused transposed pose-GEMM + skinning ----------------
// Tile: 128 n' x 64 b. Waves 2x2: wr=(wid>>1)*64 (n'), wc=(wid&1)*32 (b).
// Phase 1: C[n'][b] = Bp[n'][:] . Amat[b][:]; acc[4][2].
// Epilogue: 4 consecutive n' = one vertex slot -> ds_write_b64 to sH[b][v][4].
// Phase 2: per batch: T = Gbf[b](16x32) x Wbf^T(32x16); lane (v=c16,m=p) holds
//   T[m][0..3]; out = T.(x,y,z,1) with h from sH.
__global__ __launch_bounds__(256)
void k_fused(const unsigned short* __restrict__ Amat,
             const unsigned short* __restrict__ Bp,
             const unsigned short* __restrict__ Gbf,
             const unsigned short* __restrict__ Wbf,
             float* __restrict__ out) {
    __shared__ unsigned short sN[NP * SAP];   // 10,240 B  (Bp rows)
    __shared__ unsigned short sM[FB * SAP];   //  5,120 B  (Amat rows)
    __shared__ unsigned short sH[FB * SHP];   // 16,896 B  ([b][v][4] bf16)
    const int tid = threadIdx.x;
    const int wid = tid >> 6, l = tid & 63;
    const int c16 = l & 15, p = l >> 4;
    const int wr = (wid >> 1) * 64;   // n' base of wave
    const int wc = (wid & 1) * 32;    // b  base of wave
    const int n0 = blockIdx.x * NP;
    const int v0 = blockIdx.x * FV;
    const int b0 = blockIdx.y * FB;

    // -------- phase 1 --------
    f32x4 acc[4][2];
#pragma unroll
    for (int i = 0; i < 4; ++i)
#pragma unroll
        for (int j = 0; j < 2; ++j) acc[i][j] = (f32x4){0.f, 0.f, 0.f, 0.f};

    // staging: thread -> N rows (srow, srow+64), M row srow; k-chunk su
    const int srow = tid >> 2;
    const int su = (tid & 3) * 8;
    const unsigned short* gN = Bp + (size_t)(n0 + srow) * KDIM + su;
    const unsigned short* gM = Amat + (size_t)(b0 + srow) * KDIM + su;
    unsigned short* wN = &sN[srow * SAP + su];
    unsigned short* wM = &sM[srow * SAP + su];

    bf16x8 rN0 = *(const bf16x8*)gN;
    bf16x8 rN1 = *(const bf16x8*)(gN + 64 * KDIM);
    bf16x8 rM0 = *(const bf16x8*)gM;

    for (int ks = 0; ks < KDIM / BK; ++ks) {
        __syncthreads();
        *(bf16x8*)wN = rN0; *(bf16x8*)(wN + 64 * SAP) = rN1;
        *(bf16x8*)wM = rM0;
        if (ks < KDIM / BK - 1) {  // prefetch next K-step (hidden under MFMA below)
            gN += BK; gM += BK;
            rN0 = *(const bf16x8*)gN;
            rN1 = *(const bf16x8*)(gN + 64 * KDIM);
            rM0 = *(const bf16x8*)gM;
        }
        __syncthreads();

        bf16x8 af[4], bfr[2];
#pragma unroll
        for (int mi = 0; mi < 4; ++mi)
            af[mi] = *(const bf16x8*)&sN[(wr + mi * 16 + c16) * SAP + p * 8];
#pragma unroll
        for (int bj = 0; bj < 2; ++bj)
            bfr[bj] = *(const bf16x8*)&sM[(wc + bj * 16 + c16) * SAP + p * 8];
#pragma unroll
        for (int mi = 0; mi < 4; ++mi)
#pragma unroll
            for (int bj = 0; bj < 2; ++bj)
                acc[mi][bj] = __builtin_amdgcn_mfma_f32_16x16x32_bf16(af[mi], bfr[bj], acc[mi][bj], 0, 0, 0);
    }

    // -------- epilogue: acc -> sH (b64 per vertex slot) --------
    __syncthreads();
    {
        const int vbase = (wid >> 1) * 16 + p;   // wr>>2 + p
#pragma unroll
        for (int mi = 0; mi < 4; ++mi) {
#pragma unroll
            for (int bj = 0; bj < 2; ++bj) {
                const int vl = vbase + mi * 4;
                const int bl = wc + bj * 16 + c16;
                uint2 u;
                u.x = pkbf(acc[mi][bj][0], acc[mi][bj][1]);
                u.y = pkbf(acc[mi][bj][2], acc[mi][bj][3]);
                *(uint2*)&sH[bl * SHP + vl * 4] = u;
            }
        }
    }
    __syncthreads();

    // -------- phase 2: skinning --------
    const bf16x8 bw0 = *(const bf16x8*)&Wbf[(size_t)(v0 + c16) * 32 + p * 8];
    const bf16x8 bw1 = *(const bf16x8*)&Wbf[(size_t)(v0 + 16 + c16) * 32 + p * 8];
    const bool st0 = (v0 + c16 < N_V) && (p < 3);
    const bool st1 = (v0 + 16 + c16 < N_V) && (p < 3);
    const int bwv = wid * 16;  // wave's local batch base
    const unsigned short* gG = Gbf + (size_t)(b0 + bwv) * 512 + c16 * 32 + p * 8;
    const unsigned short* sh = &sH[bwv * SHP + c16 * 4];
    float* o0 = out + (size_t)(b0 + bwv) * NREAL + (size_t)(v0 + c16) * 3 + p;
    float* o1 = o0 + 48;  // vertex +16 -> +48 floats

    for (int ii = 0; ii < 16; ii += 8) {
        bf16x8 ag[8];
#pragma unroll
        for (int j = 0; j < 8; ++j)
            ag[j] = *(const bf16x8*)(gG + (size_t)(ii + j) * 512);
#pragma unroll
        for (int j = 0; j < 8; ++j) {
            const f32x4 t0 = __builtin_amdgcn_mfma_f32_16x16x32_bf16(ag[j], bw0, (f32x4){0.f,0.f,0.f,0.f}, 0, 0, 0);
            const f32x4 t1 = __builtin_amdgcn_mfma_f32_16x16x32_bf16(ag[j], bw1, (f32x4){0.f,0.f,0.f,0.f}, 0, 0, 0);
            const uint2 h0 = *(const uint2*)(sh + (ii + j) * SHP);
            const uint2 h1 = *(const uint2*)(sh + (ii + j) * SHP + 64);
            const float x0 = __uint_as_float(h0.x << 16);
            const float y0 = __uint_as_float(h0.x & 0xffff0000u);
            const float z0 = __uint_as_float(h0.y << 16);
            const float x1 = __uint_as_float(h1.x << 16);
            const float y1 = __uint_as_float(h1.x & 0xffff0000u);
            const float z1 = __uint_as_float(h1.y << 16);
            const float r0 = t0[0] * x0 + t0[1] * y0 + t0[2] * z0 + t0[3];
            const float r1 = t1[0] * x1 + t1[1] * y1 + t1[2] * z1 + t1[3];
            if (st0) o0[(size_t)(ii + j) * NREAL] = r0;
            if (st1) o1[(size_t)(ii + j) * NREAL] = r1;
        }
    }
}

extern "C" void kernel_launch(void* const* d_in, const int* in_sizes, int n_in,
                              void* d_out, int out_size, void* d_ws, size_t ws_size,
                              hipStream_t stream) {
    const float* pose       = (const float*)d_in[0];
    const float* beta       = (const float*)d_in[1];
    const float* shapedirs  = (const float*)d_in[2];
    const float* posedirs   = (const float*)d_in[3];
    const float* v_template = (const float*)d_in[4];
    const float* Jreg       = (const float*)d_in[5];
    const float* weights    = (const float*)d_in[6];
    float* out = (float*)d_out;

    const int B = in_sizes[0] / 72;  // 1024

    float* ws      = (float*)d_ws;
    float* partial = ws + WS_PARTIAL;
    float* JS      = ws + WS_JS;
    float* Jt      = ws + WS_JT;
    unsigned short* ubase = (unsigned short*)(ws + WS_USHORT);
    unsigned short* Amat = ubase + U_AMAT;
    unsigned short* Bp   = ubase + U_BP;
    unsigned short* Gbf  = ubase + U_GBF;
    unsigned short* Wbf  = ubase + U_WBF;

    k_jreg_partial<<<dim3(24, 8), 256, 0, stream>>>(Jreg, shapedirs, v_template, partial);
    k_jreg_final<<<24, 64, 0, stream>>>(partial, JS, Jt);
    k_prep<<<BP_BLOCKS + WBF_BLOCKS, 256, 0, stream>>>(posedirs, shapedirs, v_template,
                                                       weights, Bp, Wbf);
    k_joints<<<B, 64, 0, stream>>>(pose, beta, JS, Jt, Amat, Gbf);
    k_fused<<<dim3(NVPAD / FV, B / FB), 256, 0, stream>>>(Amat, Bp, Gbf, Wbf, out);
}